// Round 9
// baseline (172.525 us; speedup 1.0000x reference)
//
#include <hip/hip_runtime.h>
#include <hip/hip_bf16.h>
#include <stdint.h>

// Problem constants
#define B_   4
#define T_   2048
#define H_   16
#define MTOT (B_ * T_)          // 8192 rows
#define NQKV 3072               // fused QKV output cols
#define QSC  0.18033688f        // 0.125 * log2(e): fold softmax scale + exp2 conversion into Q

typedef __attribute__((ext_vector_type(8))) __bf16 bf16x8;
typedef __attribute__((ext_vector_type(4))) float f32x4;
typedef __attribute__((ext_vector_type(16))) float f32x16;
typedef __attribute__((ext_vector_type(4))) float f4v;
typedef __attribute__((ext_vector_type(4))) unsigned short us4;
typedef __attribute__((ext_vector_type(8))) unsigned short us8;
typedef __attribute__((ext_vector_type(4))) unsigned int u32x4;

static __device__ __forceinline__ unsigned short f2bf(float f) {
  __hip_bfloat16 h = __float2bfloat16(f);
  return __builtin_bit_cast(unsigned short, h);
}

static __device__ __forceinline__ float fast_exp2(float x) {
#if __has_builtin(__builtin_amdgcn_exp2f)
  return __builtin_amdgcn_exp2f(x);
#else
  float r; asm("v_exp_f32 %0, %1" : "=v"(r) : "v"(x)); return r;
#endif
}

static __device__ __forceinline__ void async16(const void* g, void* l) {
  __builtin_amdgcn_global_load_lds(
      (const __attribute__((address_space(1))) void*)g,
      (__attribute__((address_space(3))) void*)l, 16, 0, 0);
}

#define SB0() __builtin_amdgcn_sched_barrier(0)

// cross-half (lane ^ 32) reduce via permlane32_swap (VALU) instead of
// ds_bpermute (__shfl_xor).
#define XHALF(res, x, OP)                                  \
  {                                                        \
    float t1_ = (x), t2_ = (x);                            \
    asm("" : "+v"(t2_));                                   \
    asm("v_permlane32_swap_b32 %0, %1" : "+v"(t1_), "+v"(t2_)); \
    res = OP(t1_, t2_);                                    \
  }
static __device__ __forceinline__ float fadd_(float a, float b) { return a + b; }

// ---------------- fused fp32 -> bf16 convert (x4 vectorized, 1 launch) --------
__global__ __launch_bounds__(256) void cvt_all(
    const float* __restrict__ x, const float* __restrict__ Wq,
    const float* __restrict__ Wk, const float* __restrict__ Wv,
    const float* __restrict__ Wo, unsigned short* __restrict__ xb,
    unsigned short* __restrict__ wqkv, unsigned short* __restrict__ wo) {
  int i = blockIdx.x * blockDim.x + threadIdx.x;
  const float* s; unsigned short* d; int j;
  if (i < 2097152)      { s = x;  d = xb;             j = i; }
  else if (i < 2359296) { s = Wq; d = wqkv;           j = i - 2097152; }
  else if (i < 2621440) { s = Wk; d = wqkv + 1048576; j = i - 2359296; }
  else if (i < 2883584) { s = Wv; d = wqkv + 2097152; j = i - 2621440; }
  else                  { s = Wo; d = wo;             j = i - 2883584; }
  f4v v = reinterpret_cast<const f4v*>(s)[j];
  us4 o;
  o.x = f2bf(v.x); o.y = f2bf(v.y); o.z = f2bf(v.z); o.w = f2bf(v.w);
  reinterpret_cast<us4*>(d)[j] = o;
}

// ---------------- bf16 GEMM (m97 2-barrier structure, BK=64), C = A * B^T ----
// BK=64, both-sides LDS K-slot XOR swizzle (0 bank conflicts), XCD-chunked
// 1D grid. MODE 0: bf16 out, cols<1024 scaled by QSC. MODE 1: f32 out + bias.
template <int MODE, int NT>
__global__ __launch_bounds__(256) void gemm_bt(
    const unsigned short* __restrict__ A,   // [M][K] bf16 bits
    const unsigned short* __restrict__ Bw,  // [N][K] bf16 bits
    unsigned short* __restrict__ Cb,        // bf16 out (MODE 0)
    float* __restrict__ Cf,                 // f32 out (MODE 1)
    const float* __restrict__ bias,         // MODE 1
    int K, int N) {
  __shared__ __align__(16) unsigned short As[128 * 64];
  __shared__ __align__(16) unsigned short Bs[128 * 64];

  const int bid = blockIdx.x;
  const int xcd = bid & 7;
  const int loc = bid >> 3;
  const int m0 = (xcd * 8 + loc / NT) * 128;
  const int n0 = (loc % NT) * 128;

  const int t = threadIdx.x;
  const int lane = t & 63;
  const int w = t >> 6;
  const int lr = lane & 15;
  const int lg = lane >> 4;
  const int wm = w >> 1;
  const int wn = w & 1;

  f32x4 acc[4][4];
#pragma unroll
  for (int i = 0; i < 4; ++i)
#pragma unroll
    for (int j = 0; j < 4; ++j) acc[i][j] = (f32x4){0.f, 0.f, 0.f, 0.f};

  const int srow = t >> 3;
  const int gs = (t & 7) ^ ((t >> 3) & 7);       // inverse-swizzled source slot
  const unsigned short* ga = A + (size_t)(m0 + srow) * K + gs * 8;
  const unsigned short* gb = Bw + (size_t)(n0 + srow) * K + gs * 8;

  const int rsw = lr & 7;

  for (int k0 = 0; k0 < K; k0 += 64) {
#pragma unroll
    for (int k = 0; k < 4; ++k) {
      async16(ga + (size_t)(k * 32) * K + k0, &As[(k * 256 + t) * 8]);
      async16(gb + (size_t)(k * 32) * K + k0, &Bs[(k * 256 + t) * 8]);
    }
    __syncthreads();

#pragma unroll
    for (int kk = 0; kk < 2; ++kk) {
      const int slot = ((kk * 4 + lg) ^ rsw) * 8;
      bf16x8 af[4], bfr[4];
#pragma unroll
      for (int mi = 0; mi < 4; ++mi)
        af[mi] = *(const bf16x8*)&As[(wm * 64 + mi * 16 + lr) * 64 + slot];
#pragma unroll
      for (int ni = 0; ni < 4; ++ni)
        bfr[ni] = *(const bf16x8*)&Bs[(wn * 64 + ni * 16 + lr) * 64 + slot];
#pragma unroll
      for (int mi = 0; mi < 4; ++mi)
#pragma unroll
        for (int ni = 0; ni < 4; ++ni)
          acc[mi][ni] = __builtin_amdgcn_mfma_f32_16x16x32_bf16(
              af[mi], bfr[ni], acc[mi][ni], 0, 0, 0);
    }
    __syncthreads();
  }

#pragma unroll
  for (int mi = 0; mi < 4; ++mi) {
    const int row = m0 + wm * 64 + mi * 16 + lg * 4;
#pragma unroll
    for (int ni = 0; ni < 4; ++ni) {
      const int col = n0 + wn * 64 + ni * 16 + lr;
#pragma unroll
      for (int r = 0; r < 4; ++r) {
        if (MODE == 1) {
          Cf[(size_t)(row + r) * N + col] = acc[mi][ni][r] + bias[col];
        } else {
          float v = acc[mi][ni][r];
          if (col < 1024) v *= QSC;
          Cb[(size_t)(row + r) * N + col] = f2bf(v);
        }
      }
    }
  }
}

// ---------------- causal flash attention (4 waves x 32 q-rows, 32x32 MFMA) ----
// Depth-2 K prefetch across raw s_barrier (counted-vmcnt stays implicit:
// issue order V(kt+1) THEN K(kt+2) makes the compiler's auto-wait before
// VSCATTER = vmcnt(2), leaving K(kt+2) in flight across the barrier).
// 3 rotating LDS buffer sets (48KB -> 3 blocks/CU).
__global__ __launch_bounds__(256, 3) void attn_kernel(
    const unsigned short* __restrict__ qkv, unsigned short* __restrict__ ob) {
  const int bid = blockIdx.x;
  const int pair = bid & 63;
  const int g = bid >> 6;               // 0..15, dispatch round-major
  const int rnd = g >> 2, idx = g & 3;
  const int qg = (rnd == 0) ? (15 - idx)
               : (rnd == 1) ? (8 + idx)
               : (rnd == 2) ? (7 - idx) : idx;   // heavy blocks first
  const int b = pair >> 4;
  const int h = pair & 15;
  const int t = threadIdx.x;
  const int w = t >> 6;                 // 0..3
  const int lane = t & 63;
  const int l31 = lane & 31;
  const int hi = lane >> 5;

  const int q0w = qg * 128 + w * 32;       // wave's q strip
  const int myBound = 2 * qg + (w >> 1);   // last kv-tile this wave computes
  const int NT = 2 * qg + 2;               // 64-row kv tiles staged by block

  __shared__ __align__(16) unsigned short KsAll[3 * 64 * 64];
  __shared__ __align__(16) unsigned short VsAll[3 * 64 * 64];  // V^T, swizzled

  const size_t rowbase = (size_t)(b * T_) * NQKV;

  // ---- Q B-fragments: col=q=l31, k=d = m*16 + hi*8 + i ----
  bf16x8 Qf[4];
  {
    const unsigned short* qp =
        qkv + rowbase + (size_t)(q0w + l31) * NQKV + h * 64 + hi * 8;
#pragma unroll
    for (int m = 0; m < 4; ++m) Qf[m] = *(const bf16x8*)(qp + m * 16);
  }

  // ---- staging geometry (256 threads) ----
  const int kr = t >> 3;                // 0..31
  const int ks = t & 7;
  const unsigned short* kbase =
      qkv + rowbase + 1024 + h * 64 + (ks ^ (kr & 7)) * 8 + (size_t)kr * NQKV;
  const int kvr = t >> 2;               // 0..63
  const int dc2 = (t & 3) * 2;
  const unsigned short* vbase =
      qkv + rowbase + 2048 + h * 64 + dc2 * 8 + (size_t)kvr * NQKV;

  float m_i = -INFINITY, l_i = 0.f;
  f32x16 o[2];
#pragma unroll
  for (int r = 0; r < 16; ++r) { o[0][r] = 0.f; o[1][r] = 0.f; }

#define VSCATTER(Vb, v0, v1)                                       \
  {                                                                \
    _Pragma("unroll") for (int i = 0; i < 8; ++i) {                \
      const int s0 = ((kvr >> 3) ^ dc2 ^ i) & 7;                   \
      const int s1 = ((kvr >> 3) ^ (dc2 + 1) ^ i) & 7;             \
      (Vb)[(dc2 * 8 + i) * 64 + s0 * 8 + (kvr & 7)] = (v0)[i];     \
      (Vb)[((dc2 + 1) * 8 + i) * 64 + s1 * 8 + (kvr & 7)] = (v1)[i]; \
    }                                                              \
  }

  // ---- prologue: K(0) issue, V(0) load, K(1) issue, scatter V(0) ----
  {
    async16(kbase, &KsAll[t * 8]);                               // K(0)
    async16(kbase + (size_t)32 * NQKV, &KsAll[2048 + t * 8]);
    us8 v0 = *(const us8*)vbase;                                 // V(0)
    us8 v1 = *(const us8*)(vbase + 8);
    async16(kbase + (size_t)64 * NQKV, &KsAll[4096 + t * 8]);    // K(1)
    async16(kbase + (size_t)96 * NQKV, &KsAll[4096 + 2048 + t * 8]);
    VSCATTER(&VsAll[0], v0, v1);   // auto-wait leaves K(1) in flight
    asm volatile("s_waitcnt lgkmcnt(0)" ::: "memory");
    SB0();
    __builtin_amdgcn_s_barrier();
    SB0();
  }

  int bcur = 0, bnx1 = 4096, bnx2 = 8192;   // rotating LDS buffer offsets

  for (int kt = 0; kt < NT; ++kt) {
    const bool haveV = (kt + 1 < NT);
    const bool haveK = (kt + 2 < NT);

    // pt1: issue V(kt+1) FIRST, then K(kt+2) (order -> counted wait later)
    us8 w0, w1;
    if (haveV) {
      const size_t off1 = (size_t)(kt + 1) * 64 * NQKV;
      w0 = *(const us8*)(vbase + off1);
      w1 = *(const us8*)(vbase + off1 + 8);
    }
    if (haveK) {
      const size_t off2 = (size_t)(kt + 2) * 64 * NQKV;
      async16(kbase + off2, &KsAll[bnx2 + t * 8]);
      async16(kbase + off2 + (size_t)32 * NQKV, &KsAll[bnx2 + 2048 + t * 8]);
    }

    // pt2: compute on buffer bcur
    if (kt <= myBound) {
      const unsigned short* Kb = &KsAll[bcur];
      const unsigned short* Vb = &VsAll[bcur];

      f32x16 a0, a1;
#pragma unroll
      for (int r = 0; r < 16; ++r) { a0[r] = 0.f; a1[r] = 0.f; }
      {
        const int rb0 = l31 * 64;
        const int rb1 = (32 + l31) * 64;
        const int r7 = l31 & 7;
        __builtin_amdgcn_s_setprio(1);
#pragma unroll
        for (int m = 0; m < 4; ++m) {
          const int c = (((m << 1) | hi) ^ r7) * 8;
          bf16x8 kf0 = *(const bf16x8*)&Kb[rb0 + c];
          bf16x8 kf1 = *(const bf16x8*)&Kb[rb1 + c];
          a0 = __builtin_amdgcn_mfma_f32_32x32x16_bf16(kf0, Qf[m], a0, 0, 0, 0);
          a1 = __builtin_amdgcn_mfma_f32_32x32x16_bf16(kf1, Qf[m], a1, 0, 0, 0);
        }
        __builtin_amdgcn_s_setprio(0);
      }

      if (kt == myBound) {
        const int qglob = q0w + l31;
#pragma unroll
        for (int r = 0; r < 16; ++r) {
          const int kvb = kt * 64 + (r & 3) + ((r >> 2) << 3) + (hi << 2);
          if (kvb > qglob) a0[r] = -INFINITY;
          if (kvb + 32 > qglob) a1[r] = -INFINITY;
        }
      }

      // online softmax: tree max, defer-max (THR=8 in log2 space)
      float m8[8];
#pragma unroll
      for (int j = 0; j < 8; ++j)
        m8[j] = fmaxf(fmaxf(a0[j], a0[j + 8]), fmaxf(a1[j], a1[j + 8]));
      float pp = fmaxf(fmaxf(fmaxf(m8[0], m8[4]), fmaxf(m8[1], m8[5])),
                       fmaxf(fmaxf(m8[2], m8[6]), fmaxf(m8[3], m8[7])));
      float pmax;
      XHALF(pmax, pp, fmaxf);
      if (__any(pmax > m_i + 8.f)) {
        const float mnew = fmaxf(m_i, pmax);
        const float al = fast_exp2(m_i - mnew);
        m_i = mnew;
        l_i *= al;
#pragma unroll
        for (int r = 0; r < 16; ++r) { o[0][r] *= al; o[1][r] *= al; }
      }

#pragma unroll
      for (int r = 0; r < 16; ++r) {
        a0[r] = fast_exp2(a0[r] - m_i);
        a1[r] = fast_exp2(a1[r] - m_i);
      }
      float s8[8];
#pragma unroll
      for (int j = 0; j < 8; ++j)
        s8[j] = (a0[j] + a0[j + 8]) + (a1[j] + a1[j + 8]);
      float rp = ((s8[0] + s8[1]) + (s8[2] + s8[3])) +
                 ((s8[4] + s8[5]) + (s8[6] + s8[7]));
      float rs;
      XHALF(rs, rp, fadd_);
      l_i += rs;

      // P^T B-fragments: cvt_pk pairs + permlane32_swap half-exchange
      bf16x8 Pf[4];
#pragma unroll
      for (int m = 0; m < 4; ++m) {
        const int rb2 = (m & 1) * 8;
        uint32_t u0, u1, u2, u3;
        const f32x16& s = (m >> 1) ? a1 : a0;
        asm("v_cvt_pk_bf16_f32 %0, %1, %2" : "=v"(u0) : "v"(s[rb2 + 0]), "v"(s[rb2 + 1]));
        asm("v_cvt_pk_bf16_f32 %0, %1, %2" : "=v"(u1) : "v"(s[rb2 + 2]), "v"(s[rb2 + 3]));
        asm("v_cvt_pk_bf16_f32 %0, %1, %2" : "=v"(u2) : "v"(s[rb2 + 4]), "v"(s[rb2 + 5]));
        asm("v_cvt_pk_bf16_f32 %0, %1, %2" : "=v"(u3) : "v"(s[rb2 + 6]), "v"(s[rb2 + 7]));
        asm("v_permlane32_swap_b32 %0, %1" : "+v"(u0), "+v"(u2));
        asm("v_permlane32_swap_b32 %0, %1" : "+v"(u1), "+v"(u3));
        u32x4 pw = {u0, u1, u2, u3};
        Pf[m] = __builtin_bit_cast(bf16x8, pw);
      }

      // O^T += V^T P^T
      __builtin_amdgcn_s_setprio(1);
#pragma unroll
      for (int dt = 0; dt < 2; ++dt) {
        const int d = dt * 32 + l31;
        const int base = d * 64;
        const int dsw = ((d >> 3) ^ d) & 7;
#pragma unroll
        for (int m = 0; m < 4; ++m) {
          bf16x8 vf = *(const bf16x8*)&Vb[base + ((((m << 1) | hi) ^ dsw) & 7) * 8];
          o[dt] = __builtin_amdgcn_mfma_f32_32x32x16_bf16(vf, Pf[m], o[dt], 0, 0, 0);
        }
      }
      __builtin_amdgcn_s_setprio(0);
    }

    // pt3: scatter V(kt+1); auto-wait = vmcnt(2) -> K(kt+2) stays in flight
    if (haveV) VSCATTER(&VsAll[bnx1], w0, w1);

    asm volatile("s_waitcnt lgkmcnt(0)" ::: "memory");
    SB0();
    __builtin_amdgcn_s_barrier();
    SB0();

    const int tmp = bcur; bcur = bnx1; bnx1 = bnx2; bnx2 = tmp;
  }

  // ---- epilogue: normalize, pack to bf16, swap to contiguous d-runs, store --
  const float rl = 1.0f / l_i;
#pragma unroll
  for (int dt = 0; dt < 2; ++dt) {
    float s[16];
#pragma unroll
    for (int r = 0; r < 16; ++r) s[r] = o[dt][r] * rl;
    uint32_t u[8];
#pragma unroll
    for (int p = 0; p < 8; ++p)
      asm("v_cvt_pk_bf16_f32 %0, %1, %2" : "=v"(u[p]) : "v"(s[2 * p]), "v"(s[2 * p + 1]));
    asm("v_permlane32_swap_b32 %0, %1" : "+v"(u[0]), "+v"(u[2]));
    asm("v_permlane32_swap_b32 %0, %1" : "+v"(u[1]), "+v"(u[3]));
    asm("v_permlane32_swap_b32 %0, %1" : "+v"(u[4]), "+v"(u[6]));
    asm("v_permlane32_swap_b32 %0, %1" : "+v"(u[5]), "+v"(u[7]));
    unsigned short* op =
        ob + (size_t)(b * T_ + q0w + l31) * 1024 + h * 64 + dt * 32 + hi * 8;
    u32x4 c0 = {u[0], u[1], u[2], u[3]};   // d = dt*32 + hi*8 + [0..8)
    u32x4 c1 = {u[4], u[5], u[6], u[7]};   // d = dt*32 + 16 + hi*8 + [0..8)
    *(u32x4*)op = c0;
    *(u32x4*)(op + 16) = c1;
  }
}

// ---------------- host launch ----------------
extern "C" void kernel_launch(void* const* d_in, const int* in_sizes, int n_in,
                              void* d_out, int out_size, void* d_ws,
                              size_t ws_size, hipStream_t stream) {
  const float* x = (const float*)d_in[0];
  const float* Wq = (const float*)d_in[1];
  const float* Wk = (const float*)d_in[2];
  const float* Wv = (const float*)d_in[3];
  const float* Wo = (const float*)d_in[4];
  const float* bo = (const float*)d_in[5];
  float* out = (float*)d_out;

  char* ws = (char*)d_ws;
  unsigned short* xb   = (unsigned short*)(ws + 0);          // 16 MB
  unsigned short* wqkv = (unsigned short*)(ws + 16777216);   // 6 MB
  unsigned short* wo   = (unsigned short*)(ws + 23068672);   // 2 MB
  unsigned short* qkv  = (unsigned short*)(ws + 25165824);   // 48 MB
  unsigned short* ob   = (unsigned short*)(ws + 75497472);   // 16 MB
  if (ws_size < 92274688u) return;

  cvt_all<<<12288, 256, 0, stream>>>(x, Wq, Wk, Wv, Wo, xb, wqkv, wo);

  // fused QKV projection: BK=64, both-sides swizzle, XCD m-chunked grid
  gemm_bt<0, 24><<<1536, 256, 0, stream>>>(
      xb, wqkv, qkv, nullptr, nullptr, 1024, NQKV);

  // causal flash attention (depth-2 K prefetch, 3 LDS buffers, 3 blocks/CU)
  attn_kernel<<<dim3(1024), 256, 0, stream>>>(qkv, ob);

  // output projection + bias
  gemm_bt<1, 8><<<512, 256, 0, stream>>>(
      ob, wo, nullptr, out, bo, 1024, 1024);
}

// Round 11
// 169.953 us; speedup vs baseline: 1.0151x; 1.0151x over previous
//
#include <hip/hip_runtime.h>
#include <hip/hip_bf16.h>
#include <stdint.h>

// Problem constants
#define B_   4
#define T_   2048
#define H_   16
#define MTOT (B_ * T_)          // 8192 rows
#define NQKV 3072               // fused QKV output cols
#define QSC  0.18033688f        // 0.125 * log2(e): fold softmax scale + exp2 conversion into Q

typedef __attribute__((ext_vector_type(8))) __bf16 bf16x8;
typedef __attribute__((ext_vector_type(4))) float f32x4;
typedef __attribute__((ext_vector_type(16))) float f32x16;
typedef __attribute__((ext_vector_type(4))) float f4v;
typedef __attribute__((ext_vector_type(4))) unsigned short us4;
typedef __attribute__((ext_vector_type(8))) unsigned short us8;
typedef __attribute__((ext_vector_type(4))) unsigned int u32x4;

static __device__ __forceinline__ unsigned short f2bf(float f) {
  __hip_bfloat16 h = __float2bfloat16(f);
  return __builtin_bit_cast(unsigned short, h);
}

static __device__ __forceinline__ float fast_exp2(float x) {
#if __has_builtin(__builtin_amdgcn_exp2f)
  return __builtin_amdgcn_exp2f(x);
#else
  float r; asm("v_exp_f32 %0, %1" : "=v"(r) : "v"(x)); return r;
#endif
}

static __device__ __forceinline__ void async16(const void* g, void* l) {
  __builtin_amdgcn_global_load_lds(
      (const __attribute__((address_space(1))) void*)g,
      (__attribute__((address_space(3))) void*)l, 16, 0, 0);
}

// cross-half (lane ^ 32) reduce via permlane32_swap (VALU) instead of
// ds_bpermute (__shfl_xor).
#define XHALF(res, x, OP)                                  \
  {                                                        \
    float t1_ = (x), t2_ = (x);                            \
    asm("" : "+v"(t2_));                                   \
    asm("v_permlane32_swap_b32 %0, %1" : "+v"(t1_), "+v"(t2_)); \
    res = OP(t1_, t2_);                                    \
  }
static __device__ __forceinline__ float fadd_(float a, float b) { return a + b; }

// ---------------- fused fp32 -> bf16 convert (x4 vectorized, 1 launch) --------
__global__ __launch_bounds__(256) void cvt_all(
    const float* __restrict__ x, const float* __restrict__ Wq,
    const float* __restrict__ Wk, const float* __restrict__ Wv,
    const float* __restrict__ Wo, unsigned short* __restrict__ xb,
    unsigned short* __restrict__ wqkv, unsigned short* __restrict__ wo) {
  int i = blockIdx.x * blockDim.x + threadIdx.x;
  const float* s; unsigned short* d; int j;
  if (i < 2097152)      { s = x;  d = xb;             j = i; }
  else if (i < 2359296) { s = Wq; d = wqkv;           j = i - 2097152; }
  else if (i < 2621440) { s = Wk; d = wqkv + 1048576; j = i - 2359296; }
  else if (i < 2883584) { s = Wv; d = wqkv + 2097152; j = i - 2621440; }
  else                  { s = Wo; d = wo;             j = i - 2883584; }
  f4v v = reinterpret_cast<const f4v*>(s)[j];
  us4 o;
  o.x = f2bf(v.x); o.y = f2bf(v.y); o.z = f2bf(v.z); o.w = f2bf(v.w);
  reinterpret_cast<us4*>(d)[j] = o;
}

// ---------------- bf16 GEMM (m97 2-barrier structure, BK=64), C = A * B^T ----
// BK=64, both-sides LDS K-slot XOR swizzle (0 bank conflicts), XCD-chunked
// 1D grid. MODE 0: bf16 out, cols<1024 scaled by QSC. MODE 1: f32 out + bias.
template <int MODE, int NT>
__global__ __launch_bounds__(256) void gemm_bt(
    const unsigned short* __restrict__ A,   // [M][K] bf16 bits
    const unsigned short* __restrict__ Bw,  // [N][K] bf16 bits
    unsigned short* __restrict__ Cb,        // bf16 out (MODE 0)
    float* __restrict__ Cf,                 // f32 out (MODE 1)
    const float* __restrict__ bias,         // MODE 1
    int K, int N) {
  __shared__ __align__(16) unsigned short As[128 * 64];
  __shared__ __align__(16) unsigned short Bs[128 * 64];

  const int bid = blockIdx.x;
  const int xcd = bid & 7;
  const int loc = bid >> 3;
  const int m0 = (xcd * 8 + loc / NT) * 128;
  const int n0 = (loc % NT) * 128;

  const int t = threadIdx.x;
  const int lane = t & 63;
  const int w = t >> 6;
  const int lr = lane & 15;
  const int lg = lane >> 4;
  const int wm = w >> 1;
  const int wn = w & 1;

  f32x4 acc[4][4];
#pragma unroll
  for (int i = 0; i < 4; ++i)
#pragma unroll
    for (int j = 0; j < 4; ++j) acc[i][j] = (f32x4){0.f, 0.f, 0.f, 0.f};

  const int srow = t >> 3;
  const int gs = (t & 7) ^ ((t >> 3) & 7);       // inverse-swizzled source slot
  const unsigned short* ga = A + (size_t)(m0 + srow) * K + gs * 8;
  const unsigned short* gb = Bw + (size_t)(n0 + srow) * K + gs * 8;

  const int rsw = lr & 7;

  for (int k0 = 0; k0 < K; k0 += 64) {
#pragma unroll
    for (int k = 0; k < 4; ++k) {
      async16(ga + (size_t)(k * 32) * K + k0, &As[(k * 256 + t) * 8]);
      async16(gb + (size_t)(k * 32) * K + k0, &Bs[(k * 256 + t) * 8]);
    }
    __syncthreads();

#pragma unroll
    for (int kk = 0; kk < 2; ++kk) {
      const int slot = ((kk * 4 + lg) ^ rsw) * 8;
      bf16x8 af[4], bfr[4];
#pragma unroll
      for (int mi = 0; mi < 4; ++mi)
        af[mi] = *(const bf16x8*)&As[(wm * 64 + mi * 16 + lr) * 64 + slot];
#pragma unroll
      for (int ni = 0; ni < 4; ++ni)
        bfr[ni] = *(const bf16x8*)&Bs[(wn * 64 + ni * 16 + lr) * 64 + slot];
#pragma unroll
      for (int mi = 0; mi < 4; ++mi)
#pragma unroll
        for (int ni = 0; ni < 4; ++ni)
          acc[mi][ni] = __builtin_amdgcn_mfma_f32_16x16x32_bf16(
              af[mi], bfr[ni], acc[mi][ni], 0, 0, 0);
    }
    __syncthreads();
  }

#pragma unroll
  for (int mi = 0; mi < 4; ++mi) {
    const int row = m0 + wm * 64 + mi * 16 + lg * 4;
#pragma unroll
    for (int ni = 0; ni < 4; ++ni) {
      const int col = n0 + wn * 64 + ni * 16 + lr;
#pragma unroll
      for (int r = 0; r < 4; ++r) {
        if (MODE == 1) {
          Cf[(size_t)(row + r) * N + col] = acc[mi][ni][r] + bias[col];
        } else {
          float v = acc[mi][ni][r];
          if (col < 1024) v *= QSC;
          Cb[(size_t)(row + r) * N + col] = f2bf(v);
        }
      }
    }
  }
}

// ---------------- causal flash attention (4 waves x 32 q-rows, 32x32 MFMA) ----
// qkv: [8192][3072] bf16 (cols: 0..1023 Q (pre-scaled), 1024..2047 K, 2048..3071 V)
// ob : [8192][1024] bf16 attention output (col = h*64+d)
//
// 1024 blocks = 64 (b,h) pairs x 16 q-groups of 128 rows; 4 waves x 32 q-rows.
// KVBLK=64, 32KB LDS -> 4 blocks/CU, whole grid co-resident; snake qg mapping
// makes per-CU work sums constant. (Round-10's XCD-pair remap caused
// post-timing divergence -- reverted to this twice-validated mapping.)
__global__ __launch_bounds__(256, 4) void attn_kernel(
    const unsigned short* __restrict__ qkv, unsigned short* __restrict__ ob) {
  const int bid = blockIdx.x;
  const int pair = bid & 63;
  const int g = bid >> 6;               // 0..15, dispatch round-major
  const int rnd = g >> 2, idx = g & 3;
  const int qg = (rnd == 0) ? (15 - idx)
               : (rnd == 1) ? (8 + idx)
               : (rnd == 2) ? (7 - idx) : idx;   // CU sums constant
  const int b = pair >> 4;
  const int h = pair & 15;
  const int t = threadIdx.x;
  const int w = t >> 6;                 // 0..3
  const int lane = t & 63;
  const int l31 = lane & 31;
  const int hi = lane >> 5;

  const int q0w = qg * 128 + w * 32;       // wave's q strip
  const int myBound = 2 * qg + (w >> 1);   // last kv-tile this wave computes
  const int NT = 2 * qg + 2;               // 64-row kv tiles staged by block

  __shared__ __align__(16) unsigned short Ks[2][64 * 64];
  __shared__ __align__(16) unsigned short Vs[2][64 * 64];   // V^T [d][kv], swizzled

  const size_t rowbase = (size_t)(b * T_) * NQKV;

  // ---- Q B-fragments: col=q=l31, k=d = m*16 + hi*8 + i ----
  bf16x8 Qf[4];
  {
    const unsigned short* qp =
        qkv + rowbase + (size_t)(q0w + l31) * NQKV + h * 64 + hi * 8;
#pragma unroll
    for (int m = 0; m < 4; ++m) Qf[m] = *(const bf16x8*)(qp + m * 16);
  }

  // ---- staging geometry (256 threads) ----
  const int kr = t >> 3;                // 0..31
  const int ks = t & 7;
  const unsigned short* kbase =
      qkv + rowbase + 1024 + h * 64 + (ks ^ (kr & 7)) * 8 + (size_t)kr * NQKV;
  const int kvr = t >> 2;               // 0..63
  const int dc2 = (t & 3) * 2;
  const unsigned short* vbase =
      qkv + rowbase + 2048 + h * 64 + dc2 * 8 + (size_t)kvr * NQKV;

  float m_i = -INFINITY, l_i = 0.f;
  f32x16 o[2];
#pragma unroll
  for (int r = 0; r < 16; ++r) { o[0][r] = 0.f; o[1][r] = 0.f; }

#define VSCATTER(Vb, v0, v1)                                       \
  {                                                                \
    _Pragma("unroll") for (int i = 0; i < 8; ++i) {                \
      const int s0 = ((kvr >> 3) ^ dc2 ^ i) & 7;                   \
      const int s1 = ((kvr >> 3) ^ (dc2 + 1) ^ i) & 7;             \
      (Vb)[(dc2 * 8 + i) * 64 + s0 * 8 + (kvr & 7)] = (v0)[i];     \
      (Vb)[((dc2 + 1) * 8 + i) * 64 + s1 * 8 + (kvr & 7)] = (v1)[i]; \
    }                                                              \
  }

  // ---- prologue: stage tile 0 into buffer 0 ----
  {
    async16(kbase, &Ks[0][t * 8]);
    async16(kbase + (size_t)32 * NQKV, &Ks[0][2048 + t * 8]);
    us8 v0 = *(const us8*)vbase;
    us8 v1 = *(const us8*)(vbase + 8);
    VSCATTER(&Vs[0][0], v0, v1);
  }

  int cur = 0;
  for (int kt = 0; kt < NT; ++kt) {
    __syncthreads();  // buf[cur] ready (drains async K + V ds_writes)

    const bool pf = (kt + 1 < NT);
    us8 v0, v1;
    if (pf) {
      const size_t off = (size_t)(kt + 1) * 64 * NQKV;
      async16(kbase + off, &Ks[cur ^ 1][t * 8]);
      async16(kbase + off + (size_t)32 * NQKV, &Ks[cur ^ 1][2048 + t * 8]);
      v0 = *(const us8*)(vbase + off);
      v1 = *(const us8*)(vbase + off + 8);
    }

    if (kt <= myBound) {
      const unsigned short* Kb = Ks[cur];
      const unsigned short* Vb = Vs[cur];

      // ---- S^T[kv][q] : 2 kv-subtiles of 32 ----
      f32x16 a0, a1;
#pragma unroll
      for (int r = 0; r < 16; ++r) { a0[r] = 0.f; a1[r] = 0.f; }
      {
        const int rb0 = l31 * 64;
        const int rb1 = (32 + l31) * 64;
        const int r7 = l31 & 7;
        __builtin_amdgcn_s_setprio(1);
#pragma unroll
        for (int m = 0; m < 4; ++m) {
          const int c = (((m << 1) | hi) ^ r7) * 8;
          bf16x8 kf0 = *(const bf16x8*)&Kb[rb0 + c];
          bf16x8 kf1 = *(const bf16x8*)&Kb[rb1 + c];
          a0 = __builtin_amdgcn_mfma_f32_32x32x16_bf16(kf0, Qf[m], a0, 0, 0, 0);
          a1 = __builtin_amdgcn_mfma_f32_32x32x16_bf16(kf1, Qf[m], a1, 0, 0, 0);
        }
        __builtin_amdgcn_s_setprio(0);
      }

      // ---- causal mask: only the diagonal-crossing tile ----
      if (kt == myBound) {
        const int qglob = q0w + l31;
#pragma unroll
        for (int r = 0; r < 16; ++r) {
          const int kvb = kt * 64 + (r & 3) + ((r >> 2) << 3) + (hi << 2);
          if (kvb > qglob) a0[r] = -INFINITY;
          if (kvb + 32 > qglob) a1[r] = -INFINITY;
        }
      }

      // ---- online softmax: tree max, defer-max (THR=8 in log2 space) ----
      float m8[8];
#pragma unroll
      for (int j2 = 0; j2 < 8; ++j2)
        m8[j2] = fmaxf(fmaxf(a0[j2], a0[j2 + 8]), fmaxf(a1[j2], a1[j2 + 8]));
      float pp = fmaxf(fmaxf(fmaxf(m8[0], m8[4]), fmaxf(m8[1], m8[5])),
                       fmaxf(fmaxf(m8[2], m8[6]), fmaxf(m8[3], m8[7])));
      float pmax;
      XHALF(pmax, pp, fmaxf);
      if (__any(pmax > m_i + 8.f)) {
        const float mnew = fmaxf(m_i, pmax);
        const float al = fast_exp2(m_i - mnew);
        m_i = mnew;
        l_i *= al;
#pragma unroll
        for (int r = 0; r < 16; ++r) { o[0][r] *= al; o[1][r] *= al; }
      }

#pragma unroll
      for (int r = 0; r < 16; ++r) {
        a0[r] = fast_exp2(a0[r] - m_i);
        a1[r] = fast_exp2(a1[r] - m_i);
      }
      float s8[8];
#pragma unroll
      for (int j2 = 0; j2 < 8; ++j2)
        s8[j2] = (a0[j2] + a0[j2 + 8]) + (a1[j2] + a1[j2 + 8]);
      float rp = ((s8[0] + s8[1]) + (s8[2] + s8[3])) +
                 ((s8[4] + s8[5]) + (s8[6] + s8[7]));
      float rs;
      XHALF(rs, rp, fadd_);
      l_i += rs;

      // ---- P^T B-fragments: cvt_pk pairs + permlane32_swap half-exchange ----
      bf16x8 Pf[4];
#pragma unroll
      for (int m = 0; m < 4; ++m) {
        const int rb2 = (m & 1) * 8;
        uint32_t u0, u1, u2, u3;
        const f32x16& s = (m >> 1) ? a1 : a0;
        asm("v_cvt_pk_bf16_f32 %0, %1, %2" : "=v"(u0) : "v"(s[rb2 + 0]), "v"(s[rb2 + 1]));
        asm("v_cvt_pk_bf16_f32 %0, %1, %2" : "=v"(u1) : "v"(s[rb2 + 2]), "v"(s[rb2 + 3]));
        asm("v_cvt_pk_bf16_f32 %0, %1, %2" : "=v"(u2) : "v"(s[rb2 + 4]), "v"(s[rb2 + 5]));
        asm("v_cvt_pk_bf16_f32 %0, %1, %2" : "=v"(u3) : "v"(s[rb2 + 6]), "v"(s[rb2 + 7]));
        asm("v_permlane32_swap_b32 %0, %1" : "+v"(u0), "+v"(u2));
        asm("v_permlane32_swap_b32 %0, %1" : "+v"(u1), "+v"(u3));
        u32x4 pw = {u0, u1, u2, u3};
        Pf[m] = __builtin_bit_cast(bf16x8, pw);
      }

      // ---- O^T += V^T P^T ----
      __builtin_amdgcn_s_setprio(1);
#pragma unroll
      for (int dt = 0; dt < 2; ++dt) {
        const int d = dt * 32 + l31;
        const int base = d * 64;
        const int dsw = ((d >> 3) ^ d) & 7;
#pragma unroll
        for (int m = 0; m < 4; ++m) {
          bf16x8 vf = *(const bf16x8*)&Vb[base + ((((m << 1) | hi) ^ dsw) & 7) * 8];
          o[dt] = __builtin_amdgcn_mfma_f32_32x32x16_bf16(vf, Pf[m], o[dt], 0, 0, 0);
        }
      }
      __builtin_amdgcn_s_setprio(0);
    }

    if (pf) VSCATTER(&Vs[cur ^ 1][0], v0, v1);
    cur ^= 1;
  }

  // ---- epilogue: normalize, pack to bf16, swap to contiguous d-runs, store --
  const float rl = 1.0f / l_i;
#pragma unroll
  for (int dt = 0; dt < 2; ++dt) {
    float s[16];
#pragma unroll
    for (int r = 0; r < 16; ++r) s[r] = o[dt][r] * rl;
    uint32_t u[8];
#pragma unroll
    for (int p = 0; p < 8; ++p)
      asm("v_cvt_pk_bf16_f32 %0, %1, %2" : "=v"(u[p]) : "v"(s[2 * p]), "v"(s[2 * p + 1]));
    asm("v_permlane32_swap_b32 %0, %1" : "+v"(u[0]), "+v"(u[2]));
    asm("v_permlane32_swap_b32 %0, %1" : "+v"(u[1]), "+v"(u[3]));
    asm("v_permlane32_swap_b32 %0, %1" : "+v"(u[4]), "+v"(u[6]));
    asm("v_permlane32_swap_b32 %0, %1" : "+v"(u[5]), "+v"(u[7]));
    unsigned short* op =
        ob + (size_t)(b * T_ + q0w + l31) * 1024 + h * 64 + dt * 32 + hi * 8;
    u32x4 c0 = {u[0], u[1], u[2], u[3]};   // d = dt*32 + hi*8 + [0..8)
    u32x4 c1 = {u[4], u[5], u[6], u[7]};   // d = dt*32 + 16 + hi*8 + [0..8)
    *(u32x4*)op = c0;
    *(u32x4*)(op + 16) = c1;
  }
}

// ---------------- host launch ----------------
extern "C" void kernel_launch(void* const* d_in, const int* in_sizes, int n_in,
                              void* d_out, int out_size, void* d_ws,
                              size_t ws_size, hipStream_t stream) {
  const float* x = (const float*)d_in[0];
  const float* Wq = (const float*)d_in[1];
  const float* Wk = (const float*)d_in[2];
  const float* Wv = (const float*)d_in[3];
  const float* Wo = (const float*)d_in[4];
  const float* bo = (const float*)d_in[5];
  float* out = (float*)d_out;

  char* ws = (char*)d_ws;
  unsigned short* xb   = (unsigned short*)(ws + 0);          // 16 MB
  unsigned short* wqkv = (unsigned short*)(ws + 16777216);   // 6 MB
  unsigned short* wo   = (unsigned short*)(ws + 23068672);   // 2 MB
  unsigned short* qkv  = (unsigned short*)(ws + 25165824);   // 48 MB
  unsigned short* ob   = (unsigned short*)(ws + 75497472);   // 16 MB
  if (ws_size < 92274688u) return;

  cvt_all<<<12288, 256, 0, stream>>>(x, Wq, Wk, Wv, Wo, xb, wqkv, wo);

  // fused QKV projection: BK=64, both-sides swizzle, XCD m-chunked grid
  gemm_bt<0, 24><<<1536, 256, 0, stream>>>(
      xb, wqkv, qkv, nullptr, nullptr, 1024, NQKV);

  // causal flash attention (snake mapping, 4 blocks/CU, double-buffered)
  attn_kernel<<<dim3(1024), 256, 0, stream>>>(qkv, ob);

  // output projection + bias
  gemm_bt<1, 8><<<512, 256, 0, stream>>>(
      ob, wo, nullptr, out, bo, 1024, 1024);
}

// Round 12
// 158.034 us; speedup vs baseline: 1.0917x; 1.0754x over previous
//
#include <hip/hip_runtime.h>
#include <hip/hip_bf16.h>
#include <stdint.h>

// Problem constants
#define B_   4
#define T_   2048
#define H_   16
#define MTOT (B_ * T_)          // 8192 rows
#define NQKV 3072               // fused QKV output cols
#define QSC  0.18033688f        // 0.125 * log2(e): fold softmax scale + exp2 conversion into Q

typedef __attribute__((ext_vector_type(8))) __bf16 bf16x8;
typedef __attribute__((ext_vector_type(4))) float f32x4;
typedef __attribute__((ext_vector_type(16))) float f32x16;
typedef __attribute__((ext_vector_type(4))) float f4v;
typedef __attribute__((ext_vector_type(4))) unsigned short us4;
typedef __attribute__((ext_vector_type(8))) unsigned short us8;
typedef __attribute__((ext_vector_type(4))) unsigned int u32x4;

static __device__ __forceinline__ unsigned short f2bf(float f) {
  __hip_bfloat16 h = __float2bfloat16(f);
  return __builtin_bit_cast(unsigned short, h);
}

static __device__ __forceinline__ float fast_exp2(float x) {
#if __has_builtin(__builtin_amdgcn_exp2f)
  return __builtin_amdgcn_exp2f(x);
#else
  float r; asm("v_exp_f32 %0, %1" : "=v"(r) : "v"(x)); return r;
#endif
}

static __device__ __forceinline__ void async16(const void* g, void* l) {
  __builtin_amdgcn_global_load_lds(
      (const __attribute__((address_space(1))) void*)g,
      (__attribute__((address_space(3))) void*)l, 16, 0, 0);
}

// cross-half (lane ^ 32) reduce via permlane32_swap (VALU) instead of
// ds_bpermute (__shfl_xor).
#define XHALF(res, x, OP)                                  \
  {                                                        \
    float t1_ = (x), t2_ = (x);                            \
    asm("" : "+v"(t2_));                                   \
    asm("v_permlane32_swap_b32 %0, %1" : "+v"(t1_), "+v"(t2_)); \
    res = OP(t1_, t2_);                                    \
  }
static __device__ __forceinline__ float fadd_(float a, float b) { return a + b; }

// ---------------- fused fp32 -> bf16 convert (x4 vectorized, 1 launch) --------
__global__ __launch_bounds__(256) void cvt_all(
    const float* __restrict__ x, const float* __restrict__ Wq,
    const float* __restrict__ Wk, const float* __restrict__ Wv,
    const float* __restrict__ Wo, unsigned short* __restrict__ xb,
    unsigned short* __restrict__ wqkv, unsigned short* __restrict__ wo) {
  int i = blockIdx.x * blockDim.x + threadIdx.x;
  const float* s; unsigned short* d; int j;
  if (i < 2097152)      { s = x;  d = xb;             j = i; }
  else if (i < 2359296) { s = Wq; d = wqkv;           j = i - 2097152; }
  else if (i < 2621440) { s = Wk; d = wqkv + 1048576; j = i - 2359296; }
  else if (i < 2883584) { s = Wv; d = wqkv + 2097152; j = i - 2621440; }
  else                  { s = Wo; d = wo;             j = i - 2883584; }
  f4v v = reinterpret_cast<const f4v*>(s)[j];
  us4 o;
  o.x = f2bf(v.x); o.y = f2bf(v.y); o.z = f2bf(v.z); o.w = f2bf(v.w);
  reinterpret_cast<us4*>(d)[j] = o;
}

// ---------------- QKV GEMM: BM=128 x BN=256, BK=64, 512 threads --------------
// Same 2-barrier sync structure + both-sides K-slot XOR swizzle as the proven
// gemm_bt; geometry widened: A-refetch halves (12 n-columns instead of 24),
// staging 6 async16/thread/iter (was 8), 48KB LDS -> exactly 3 blocks/CU,
// grid 768 = fully co-resident, XCD-chunked (8 x (8 m-panels x 12 n-tiles)).
__global__ __launch_bounds__(512) void gemm_qkv(
    const unsigned short* __restrict__ A,   // [8192][1024] bf16
    const unsigned short* __restrict__ Bw,  // [3072][1024] bf16
    unsigned short* __restrict__ Cb) {      // [8192][3072] bf16, Q cols scaled
  const int K = 1024;
  __shared__ __align__(16) unsigned short As[128 * 64];
  __shared__ __align__(16) unsigned short Bs[256 * 64];

  const int bid = blockIdx.x;
  const int xcd = bid & 7;
  const int loc = bid >> 3;              // 0..95
  const int m0 = (xcd * 8 + loc / 12) * 128;
  const int n0 = (loc % 12) * 256;

  const int t = threadIdx.x;
  const int lane = t & 63;
  const int w = t >> 6;
  const int lr = lane & 15;
  const int lg = lane >> 4;
  const int wm = w >> 2;                 // 0..1
  const int wn = w & 3;                  // 0..3

  f32x4 acc[4][4];
#pragma unroll
  for (int i = 0; i < 4; ++i)
#pragma unroll
    for (int j = 0; j < 4; ++j) acc[i][j] = (f32x4){0.f, 0.f, 0.f, 0.f};

  // staging: chunk c = k*512 + t; row = k*64 + (t>>3), LDS slot = t&7.
  // slot l at row r holds global k-slot l ^ (r&7); (k*64)%8==0 so the XOR
  // term ((t>>3)&7) is k-invariant.
  const int srow = t >> 3;                      // 0..63
  const int gs = (t & 7) ^ (srow & 7);          // inverse-swizzled source slot
  const unsigned short* ga = A + (size_t)(m0 + srow) * K + gs * 8;
  const unsigned short* gb = Bw + (size_t)(n0 + srow) * K + gs * 8;
  const int rsw = lr & 7;

  for (int k0 = 0; k0 < K; k0 += 64) {
#pragma unroll
    for (int k = 0; k < 2; ++k)
      async16(ga + (size_t)(k * 64) * K + k0, &As[(k * 512 + t) * 8]);
#pragma unroll
    for (int k = 0; k < 4; ++k)
      async16(gb + (size_t)(k * 64) * K + k0, &Bs[(k * 512 + t) * 8]);
    __syncthreads();

#pragma unroll
    for (int kk = 0; kk < 2; ++kk) {
      const int slot = ((kk * 4 + lg) ^ rsw) * 8;
      bf16x8 af[4], bfr[4];
#pragma unroll
      for (int mi = 0; mi < 4; ++mi)
        af[mi] = *(const bf16x8*)&As[(wm * 64 + mi * 16 + lr) * 64 + slot];
#pragma unroll
      for (int ni = 0; ni < 4; ++ni)
        bfr[ni] = *(const bf16x8*)&Bs[(wn * 64 + ni * 16 + lr) * 64 + slot];
#pragma unroll
      for (int mi = 0; mi < 4; ++mi)
#pragma unroll
        for (int ni = 0; ni < 4; ++ni)
          acc[mi][ni] = __builtin_amdgcn_mfma_f32_16x16x32_bf16(
              af[mi], bfr[ni], acc[mi][ni], 0, 0, 0);
    }
    __syncthreads();
  }

  // epilogue: D layout col=lane&15, row=(lane>>4)*4+r ; Q cols scaled by QSC
#pragma unroll
  for (int mi = 0; mi < 4; ++mi) {
    const int row = m0 + wm * 64 + mi * 16 + lg * 4;
#pragma unroll
    for (int ni = 0; ni < 4; ++ni) {
      const int col = n0 + wn * 64 + ni * 16 + lr;
      const float sc = (col < 1024) ? QSC : 1.0f;
#pragma unroll
      for (int r = 0; r < 4; ++r)
        Cb[(size_t)(row + r) * NQKV + col] = f2bf(acc[mi][ni][r] * sc);
    }
  }
}

// ---------------- bf16 GEMM (m97 2-barrier structure, BK=64), o-proj ---------
// f32 out + bias. BK=64, both-sides K-slot XOR swizzle, XCD-chunked grid.
template <int NT>
__global__ __launch_bounds__(256) void gemm_bt(
    const unsigned short* __restrict__ A,   // [M][K] bf16 bits
    const unsigned short* __restrict__ Bw,  // [N][K] bf16 bits
    float* __restrict__ Cf,                 // f32 out
    const float* __restrict__ bias,
    int K, int N) {
  __shared__ __align__(16) unsigned short As[128 * 64];
  __shared__ __align__(16) unsigned short Bs[128 * 64];

  const int bid = blockIdx.x;
  const int xcd = bid & 7;
  const int loc = bid >> 3;
  const int m0 = (xcd * 8 + loc / NT) * 128;
  const int n0 = (loc % NT) * 128;

  const int t = threadIdx.x;
  const int lane = t & 63;
  const int w = t >> 6;
  const int lr = lane & 15;
  const int lg = lane >> 4;
  const int wm = w >> 1;
  const int wn = w & 1;

  f32x4 acc[4][4];
#pragma unroll
  for (int i = 0; i < 4; ++i)
#pragma unroll
    for (int j = 0; j < 4; ++j) acc[i][j] = (f32x4){0.f, 0.f, 0.f, 0.f};

  const int srow = t >> 3;
  const int gs = (t & 7) ^ ((t >> 3) & 7);       // inverse-swizzled source slot
  const unsigned short* ga = A + (size_t)(m0 + srow) * K + gs * 8;
  const unsigned short* gb = Bw + (size_t)(n0 + srow) * K + gs * 8;

  const int rsw = lr & 7;

  for (int k0 = 0; k0 < K; k0 += 64) {
#pragma unroll
    for (int k = 0; k < 4; ++k) {
      async16(ga + (size_t)(k * 32) * K + k0, &As[(k * 256 + t) * 8]);
      async16(gb + (size_t)(k * 32) * K + k0, &Bs[(k * 256 + t) * 8]);
    }
    __syncthreads();

#pragma unroll
    for (int kk = 0; kk < 2; ++kk) {
      const int slot = ((kk * 4 + lg) ^ rsw) * 8;
      bf16x8 af[4], bfr[4];
#pragma unroll
      for (int mi = 0; mi < 4; ++mi)
        af[mi] = *(const bf16x8*)&As[(wm * 64 + mi * 16 + lr) * 64 + slot];
#pragma unroll
      for (int ni = 0; ni < 4; ++ni)
        bfr[ni] = *(const bf16x8*)&Bs[(wn * 64 + ni * 16 + lr) * 64 + slot];
#pragma unroll
      for (int mi = 0; mi < 4; ++mi)
#pragma unroll
        for (int ni = 0; ni < 4; ++ni)
          acc[mi][ni] = __builtin_amdgcn_mfma_f32_16x16x32_bf16(
              af[mi], bfr[ni], acc[mi][ni], 0, 0, 0);
    }
    __syncthreads();
  }

#pragma unroll
  for (int mi = 0; mi < 4; ++mi) {
    const int row = m0 + wm * 64 + mi * 16 + lg * 4;
#pragma unroll
    for (int ni = 0; ni < 4; ++ni) {
      const int col = n0 + wn * 64 + ni * 16 + lr;
#pragma unroll
      for (int r = 0; r < 4; ++r)
        Cf[(size_t)(row + r) * N + col] = acc[mi][ni][r] + bias[col];
    }
  }
}

// ---------------- causal flash attention (4 waves x 32 q-rows, 32x32 MFMA) ----
// qkv: [8192][3072] bf16 (cols: 0..1023 Q (pre-scaled), 1024..2047 K, 2048..3071 V)
// ob : [8192][1024] bf16 attention output (col = h*64+d)
//
// 1024 blocks = 64 (b,h) pairs x 16 q-groups of 128 rows; 4 waves x 32 q-rows.
// KVBLK=64, 32KB LDS -> 4 blocks/CU, whole grid co-resident; snake qg mapping
// makes per-CU work sums constant. (Twice-validated configuration.)
__global__ __launch_bounds__(256, 4) void attn_kernel(
    const unsigned short* __restrict__ qkv, unsigned short* __restrict__ ob) {
  const int bid = blockIdx.x;
  const int pair = bid & 63;
  const int g = bid >> 6;               // 0..15, dispatch round-major
  const int rnd = g >> 2, idx = g & 3;
  const int qg = (rnd == 0) ? (15 - idx)
               : (rnd == 1) ? (8 + idx)
               : (rnd == 2) ? (7 - idx) : idx;   // CU sums constant
  const int b = pair >> 4;
  const int h = pair & 15;
  const int t = threadIdx.x;
  const int w = t >> 6;                 // 0..3
  const int lane = t & 63;
  const int l31 = lane & 31;
  const int hi = lane >> 5;

  const int q0w = qg * 128 + w * 32;       // wave's q strip
  const int myBound = 2 * qg + (w >> 1);   // last kv-tile this wave computes
  const int NT = 2 * qg + 2;               // 64-row kv tiles staged by block

  __shared__ __align__(16) unsigned short Ks[2][64 * 64];
  __shared__ __align__(16) unsigned short Vs[2][64 * 64];   // V^T [d][kv], swizzled

  const size_t rowbase = (size_t)(b * T_) * NQKV;

  // ---- Q B-fragments: col=q=l31, k=d = m*16 + hi*8 + i ----
  bf16x8 Qf[4];
  {
    const unsigned short* qp =
        qkv + rowbase + (size_t)(q0w + l31) * NQKV + h * 64 + hi * 8;
#pragma unroll
    for (int m = 0; m < 4; ++m) Qf[m] = *(const bf16x8*)(qp + m * 16);
  }

  // ---- staging geometry (256 threads) ----
  const int kr = t >> 3;                // 0..31
  const int ks = t & 7;
  const unsigned short* kbase =
      qkv + rowbase + 1024 + h * 64 + (ks ^ (kr & 7)) * 8 + (size_t)kr * NQKV;
  const int kvr = t >> 2;               // 0..63
  const int dc2 = (t & 3) * 2;
  const unsigned short* vbase =
      qkv + rowbase + 2048 + h * 64 + dc2 * 8 + (size_t)kvr * NQKV;

  float m_i = -INFINITY, l_i = 0.f;
  f32x16 o[2];
#pragma unroll
  for (int r = 0; r < 16; ++r) { o[0][r] = 0.f; o[1][r] = 0.f; }

#define VSCATTER(Vb, v0, v1)                                       \
  {                                                                \
    _Pragma("unroll") for (int i = 0; i < 8; ++i) {                \
      const int s0 = ((kvr >> 3) ^ dc2 ^ i) & 7;                   \
      const int s1 = ((kvr >> 3) ^ (dc2 + 1) ^ i) & 7;             \
      (Vb)[(dc2 * 8 + i) * 64 + s0 * 8 + (kvr & 7)] = (v0)[i];     \
      (Vb)[((dc2 + 1) * 8 + i) * 64 + s1 * 8 + (kvr & 7)] = (v1)[i]; \
    }                                                              \
  }

  // ---- prologue: stage tile 0 into buffer 0 ----
  {
    async16(kbase, &Ks[0][t * 8]);
    async16(kbase + (size_t)32 * NQKV, &Ks[0][2048 + t * 8]);
    us8 v0 = *(const us8*)vbase;
    us8 v1 = *(const us8*)(vbase + 8);
    VSCATTER(&Vs[0][0], v0, v1);
  }

  int cur = 0;
  for (int kt = 0; kt < NT; ++kt) {
    __syncthreads();  // buf[cur] ready (drains async K + V ds_writes)

    const bool pf = (kt + 1 < NT);
    us8 v0, v1;
    if (pf) {
      const size_t off = (size_t)(kt + 1) * 64 * NQKV;
      async16(kbase + off, &Ks[cur ^ 1][t * 8]);
      async16(kbase + off + (size_t)32 * NQKV, &Ks[cur ^ 1][2048 + t * 8]);
      v0 = *(const us8*)(vbase + off);
      v1 = *(const us8*)(vbase + off + 8);
    }

    if (kt <= myBound) {
      const unsigned short* Kb = Ks[cur];
      const unsigned short* Vb = Vs[cur];

      // ---- S^T[kv][q] : 2 kv-subtiles of 32 ----
      f32x16 a0, a1;
#pragma unroll
      for (int r = 0; r < 16; ++r) { a0[r] = 0.f; a1[r] = 0.f; }
      {
        const int rb0 = l31 * 64;
        const int rb1 = (32 + l31) * 64;
        const int r7 = l31 & 7;
        __builtin_amdgcn_s_setprio(1);
#pragma unroll
        for (int m = 0; m < 4; ++m) {
          const int c = (((m << 1) | hi) ^ r7) * 8;
          bf16x8 kf0 = *(const bf16x8*)&Kb[rb0 + c];
          bf16x8 kf1 = *(const bf16x8*)&Kb[rb1 + c];
          a0 = __builtin_amdgcn_mfma_f32_32x32x16_bf16(kf0, Qf[m], a0, 0, 0, 0);
          a1 = __builtin_amdgcn_mfma_f32_32x32x16_bf16(kf1, Qf[m], a1, 0, 0, 0);
        }
        __builtin_amdgcn_s_setprio(0);
      }

      // ---- causal mask: only the diagonal-crossing tile ----
      if (kt == myBound) {
        const int qglob = q0w + l31;
#pragma unroll
        for (int r = 0; r < 16; ++r) {
          const int kvb = kt * 64 + (r & 3) + ((r >> 2) << 3) + (hi << 2);
          if (kvb > qglob) a0[r] = -INFINITY;
          if (kvb + 32 > qglob) a1[r] = -INFINITY;
        }
      }

      // ---- online softmax: tree max, defer-max (THR=8 in log2 space) ----
      float m8[8];
#pragma unroll
      for (int j2 = 0; j2 < 8; ++j2)
        m8[j2] = fmaxf(fmaxf(a0[j2], a0[j2 + 8]), fmaxf(a1[j2], a1[j2 + 8]));
      float pp = fmaxf(fmaxf(fmaxf(m8[0], m8[4]), fmaxf(m8[1], m8[5])),
                       fmaxf(fmaxf(m8[2], m8[6]), fmaxf(m8[3], m8[7])));
      float pmax;
      XHALF(pmax, pp, fmaxf);
      if (__any(pmax > m_i + 8.f)) {
        const float mnew = fmaxf(m_i, pmax);
        const float al = fast_exp2(m_i - mnew);
        m_i = mnew;
        l_i *= al;
#pragma unroll
        for (int r = 0; r < 16; ++r) { o[0][r] *= al; o[1][r] *= al; }
      }

#pragma unroll
      for (int r = 0; r < 16; ++r) {
        a0[r] = fast_exp2(a0[r] - m_i);
        a1[r] = fast_exp2(a1[r] - m_i);
      }
      float s8[8];
#pragma unroll
      for (int j2 = 0; j2 < 8; ++j2)
        s8[j2] = (a0[j2] + a0[j2 + 8]) + (a1[j2] + a1[j2 + 8]);
      float rp = ((s8[0] + s8[1]) + (s8[2] + s8[3])) +
                 ((s8[4] + s8[5]) + (s8[6] + s8[7]));
      float rs;
      XHALF(rs, rp, fadd_);
      l_i += rs;

      // ---- P^T B-fragments: cvt_pk pairs + permlane32_swap half-exchange ----
      bf16x8 Pf[4];
#pragma unroll
      for (int m = 0; m < 4; ++m) {
        const int rb2 = (m & 1) * 8;
        uint32_t u0, u1, u2, u3;
        const f32x16& s = (m >> 1) ? a1 : a0;
        asm("v_cvt_pk_bf16_f32 %0, %1, %2" : "=v"(u0) : "v"(s[rb2 + 0]), "v"(s[rb2 + 1]));
        asm("v_cvt_pk_bf16_f32 %0, %1, %2" : "=v"(u1) : "v"(s[rb2 + 2]), "v"(s[rb2 + 3]));
        asm("v_cvt_pk_bf16_f32 %0, %1, %2" : "=v"(u2) : "v"(s[rb2 + 4]), "v"(s[rb2 + 5]));
        asm("v_cvt_pk_bf16_f32 %0, %1, %2" : "=v"(u3) : "v"(s[rb2 + 6]), "v"(s[rb2 + 7]));
        asm("v_permlane32_swap_b32 %0, %1" : "+v"(u0), "+v"(u2));
        asm("v_permlane32_swap_b32 %0, %1" : "+v"(u1), "+v"(u3));
        u32x4 pw = {u0, u1, u2, u3};
        Pf[m] = __builtin_bit_cast(bf16x8, pw);
      }

      // ---- O^T += V^T P^T ----
      __builtin_amdgcn_s_setprio(1);
#pragma unroll
      for (int dt = 0; dt < 2; ++dt) {
        const int d = dt * 32 + l31;
        const int base = d * 64;
        const int dsw = ((d >> 3) ^ d) & 7;
#pragma unroll
        for (int m = 0; m < 4; ++m) {
          bf16x8 vf = *(const bf16x8*)&Vb[base + ((((m << 1) | hi) ^ dsw) & 7) * 8];
          o[dt] = __builtin_amdgcn_mfma_f32_32x32x16_bf16(vf, Pf[m], o[dt], 0, 0, 0);
        }
      }
      __builtin_amdgcn_s_setprio(0);
    }

    if (pf) VSCATTER(&Vs[cur ^ 1][0], v0, v1);
    cur ^= 1;
  }

  // ---- epilogue: normalize, pack to bf16, swap to contiguous d-runs, store --
  const float rl = 1.0f / l_i;
#pragma unroll
  for (int dt = 0; dt < 2; ++dt) {
    float s[16];
#pragma unroll
    for (int r = 0; r < 16; ++r) s[r] = o[dt][r] * rl;
    uint32_t u[8];
#pragma unroll
    for (int p = 0; p < 8; ++p)
      asm("v_cvt_pk_bf16_f32 %0, %1, %2" : "=v"(u[p]) : "v"(s[2 * p]), "v"(s[2 * p + 1]));
    asm("v_permlane32_swap_b32 %0, %1" : "+v"(u[0]), "+v"(u[2]));
    asm("v_permlane32_swap_b32 %0, %1" : "+v"(u[1]), "+v"(u[3]));
    asm("v_permlane32_swap_b32 %0, %1" : "+v"(u[4]), "+v"(u[6]));
    asm("v_permlane32_swap_b32 %0, %1" : "+v"(u[5]), "+v"(u[7]));
    unsigned short* op =
        ob + (size_t)(b * T_ + q0w + l31) * 1024 + h * 64 + dt * 32 + hi * 8;
    u32x4 c0 = {u[0], u[1], u[2], u[3]};   // d = dt*32 + hi*8 + [0..8)
    u32x4 c1 = {u[4], u[5], u[6], u[7]};   // d = dt*32 + 16 + hi*8 + [0..8)
    *(u32x4*)op = c0;
    *(u32x4*)(op + 16) = c1;
  }
}

// ---------------- host launch ----------------
extern "C" void kernel_launch(void* const* d_in, const int* in_sizes, int n_in,
                              void* d_out, int out_size, void* d_ws,
                              size_t ws_size, hipStream_t stream) {
  const float* x = (const float*)d_in[0];
  const float* Wq = (const float*)d_in[1];
  const float* Wk = (const float*)d_in[2];
  const float* Wv = (const float*)d_in[3];
  const float* Wo = (const float*)d_in[4];
  const float* bo = (const float*)d_in[5];
  float* out = (float*)d_out;

  char* ws = (char*)d_ws;
  unsigned short* xb   = (unsigned short*)(ws + 0);          // 16 MB
  unsigned short* wqkv = (unsigned short*)(ws + 16777216);   // 6 MB
  unsigned short* wo   = (unsigned short*)(ws + 23068672);   // 2 MB
  unsigned short* qkv  = (unsigned short*)(ws + 25165824);   // 48 MB
  unsigned short* ob   = (unsigned short*)(ws + 75497472);   // 16 MB
  if (ws_size < 92274688u) return;

  cvt_all<<<12288, 256, 0, stream>>>(x, Wq, Wk, Wv, Wo, xb, wqkv, wo);

  // fused QKV projection: BM=128 x BN=256, BK=64, 768 blocks (3/CU resident)
  gemm_qkv<<<768, 512, 0, stream>>>(xb, wqkv, qkv);

  // causal flash attention (snake mapping, 4 blocks/CU, double-buffered)
  attn_kernel<<<dim3(1024), 256, 0, stream>>>(qkv, ob);

  // output projection + bias
  gemm_bt<8><<<512, 256, 0, stream>>>(ob, wo, out, bo, 1024, 1024);
}

// Round 13
// 154.235 us; speedup vs baseline: 1.1186x; 1.0246x over previous
//
#include <hip/hip_runtime.h>
#include <hip/hip_bf16.h>
#include <stdint.h>

// Problem constants
#define B_   4
#define T_   2048
#define H_   16
#define MTOT (B_ * T_)          // 8192 rows
#define NQK  2048               // QK buffer cols (Q 0..1023, K 1024..2047)
#define QSC  0.18033688f        // 0.125 * log2(e): fold softmax scale + exp2 conversion into Q

typedef __attribute__((ext_vector_type(8))) __bf16 bf16x8;
typedef __attribute__((ext_vector_type(4))) float f32x4;
typedef __attribute__((ext_vector_type(16))) float f32x16;
typedef __attribute__((ext_vector_type(4))) float f4v;
typedef __attribute__((ext_vector_type(4))) unsigned short us4;
typedef __attribute__((ext_vector_type(8))) unsigned short us8;
typedef __attribute__((ext_vector_type(4))) unsigned int u32x4;

static __device__ __forceinline__ unsigned short f2bf(float f) {
  __hip_bfloat16 h = __float2bfloat16(f);
  return __builtin_bit_cast(unsigned short, h);
}

static __device__ __forceinline__ float fast_exp2(float x) {
#if __has_builtin(__builtin_amdgcn_exp2f)
  return __builtin_amdgcn_exp2f(x);
#else
  float r; asm("v_exp_f32 %0, %1" : "=v"(r) : "v"(x)); return r;
#endif
}

static __device__ __forceinline__ void async16(const void* g, void* l) {
  __builtin_amdgcn_global_load_lds(
      (const __attribute__((address_space(1))) void*)g,
      (__attribute__((address_space(3))) void*)l, 16, 0, 0);
}

// cross-half (lane ^ 32) reduce via permlane32_swap (VALU) instead of
// ds_bpermute (__shfl_xor).
#define XHALF(res, x, OP)                                  \
  {                                                        \
    float t1_ = (x), t2_ = (x);                            \
    asm("" : "+v"(t2_));                                   \
    asm("v_permlane32_swap_b32 %0, %1" : "+v"(t1_), "+v"(t2_)); \
    res = OP(t1_, t2_);                                    \
  }
static __device__ __forceinline__ float fadd_(float a, float b) { return a + b; }

// ---------------- fused fp32 -> bf16 convert (x4 vectorized, 1 launch) --------
__global__ __launch_bounds__(256) void cvt_all(
    const float* __restrict__ x, const float* __restrict__ Wq,
    const float* __restrict__ Wk, const float* __restrict__ Wv,
    const float* __restrict__ Wo, unsigned short* __restrict__ xb,
    unsigned short* __restrict__ wqkv, unsigned short* __restrict__ wo) {
  int i = blockIdx.x * blockDim.x + threadIdx.x;
  const float* s; unsigned short* d; int j;
  if (i < 2097152)      { s = x;  d = xb;             j = i; }
  else if (i < 2359296) { s = Wq; d = wqkv;           j = i - 2097152; }
  else if (i < 2621440) { s = Wk; d = wqkv + 1048576; j = i - 2359296; }
  else if (i < 2883584) { s = Wv; d = wqkv + 2097152; j = i - 2621440; }
  else                  { s = Wo; d = wo;             j = i - 2883584; }
  f4v v = reinterpret_cast<const f4v*>(s)[j];
  us4 o;
  o.x = f2bf(v.x); o.y = f2bf(v.y); o.z = f2bf(v.z); o.w = f2bf(v.w);
  reinterpret_cast<us4*>(d)[j] = o;
}

// ---------------- QKV GEMM: BM=128 x BN=256, BK=64, 512 threads --------------
// 2-barrier structure + both-sides K-slot XOR swizzle (proven). Epilogue:
//  - n0 < 2048  (QK blocks): bf16 -> qk[8192][2048], Q cols scaled by QSC.
//  - n0 >= 2048 (V blocks):  bf16 TRANSPOSED -> vT[1024][8192]
//    (vT[col-2048][row]; 4 consecutive rows/thread -> 8B stores). This makes
//    V^T available for async16 staging in attention (no in-kernel transpose).
__global__ __launch_bounds__(512) void gemm_qkv(
    const unsigned short* __restrict__ A,    // [8192][1024] bf16
    const unsigned short* __restrict__ Bw,   // [3072][1024] bf16
    unsigned short* __restrict__ Cqk,        // [8192][2048]
    unsigned short* __restrict__ vT) {       // [1024][8192]
  const int K = 1024;
  __shared__ __align__(16) unsigned short As[128 * 64];
  __shared__ __align__(16) unsigned short Bs[256 * 64];

  const int bid = blockIdx.x;
  const int xcd = bid & 7;
  const int loc = bid >> 3;              // 0..95
  const int m0 = (xcd * 8 + loc / 12) * 128;
  const int n0 = (loc % 12) * 256;

  const int t = threadIdx.x;
  const int lane = t & 63;
  const int w = t >> 6;
  const int lr = lane & 15;
  const int lg = lane >> 4;
  const int wm = w >> 2;                 // 0..1
  const int wn = w & 3;                  // 0..3

  f32x4 acc[4][4];
#pragma unroll
  for (int i = 0; i < 4; ++i)
#pragma unroll
    for (int j = 0; j < 4; ++j) acc[i][j] = (f32x4){0.f, 0.f, 0.f, 0.f};

  const int srow = t >> 3;                      // 0..63
  const int gs = (t & 7) ^ (srow & 7);          // inverse-swizzled source slot
  const unsigned short* ga = A + (size_t)(m0 + srow) * K + gs * 8;
  const unsigned short* gb = Bw + (size_t)(n0 + srow) * K + gs * 8;
  const int rsw = lr & 7;

  for (int k0 = 0; k0 < K; k0 += 64) {
#pragma unroll
    for (int k = 0; k < 2; ++k)
      async16(ga + (size_t)(k * 64) * K + k0, &As[(k * 512 + t) * 8]);
#pragma unroll
    for (int k = 0; k < 4; ++k)
      async16(gb + (size_t)(k * 64) * K + k0, &Bs[(k * 512 + t) * 8]);
    __syncthreads();

#pragma unroll
    for (int kk = 0; kk < 2; ++kk) {
      const int slot = ((kk * 4 + lg) ^ rsw) * 8;
      bf16x8 af[4], bfr[4];
#pragma unroll
      for (int mi = 0; mi < 4; ++mi)
        af[mi] = *(const bf16x8*)&As[(wm * 64 + mi * 16 + lr) * 64 + slot];
#pragma unroll
      for (int ni = 0; ni < 4; ++ni)
        bfr[ni] = *(const bf16x8*)&Bs[(wn * 64 + ni * 16 + lr) * 64 + slot];
#pragma unroll
      for (int mi = 0; mi < 4; ++mi)
#pragma unroll
        for (int ni = 0; ni < 4; ++ni)
          acc[mi][ni] = __builtin_amdgcn_mfma_f32_16x16x32_bf16(
              af[mi], bfr[ni], acc[mi][ni], 0, 0, 0);
    }
    __syncthreads();
  }

  // epilogue: D layout col=lane&15, row=(lane>>4)*4+r
  if (n0 < 2048) {
#pragma unroll
    for (int mi = 0; mi < 4; ++mi) {
      const int row = m0 + wm * 64 + mi * 16 + lg * 4;
#pragma unroll
      for (int ni = 0; ni < 4; ++ni) {
        const int col = n0 + wn * 64 + ni * 16 + lr;
        const float sc = (col < 1024) ? QSC : 1.0f;
#pragma unroll
        for (int r = 0; r < 4; ++r)
          Cqk[(size_t)(row + r) * NQK + col] = f2bf(acc[mi][ni][r] * sc);
      }
    }
  } else {
    // V block: write transposed. vT[col2][row..row+3] (8B per fragment).
#pragma unroll
    for (int mi = 0; mi < 4; ++mi) {
      const int row = m0 + wm * 64 + mi * 16 + lg * 4;   // t-index, 4 consec
#pragma unroll
      for (int ni = 0; ni < 4; ++ni) {
        const int col2 = (n0 - 2048) + wn * 64 + ni * 16 + lr;  // dglob
        us4 pk;
#pragma unroll
        for (int r = 0; r < 4; ++r) pk[r] = f2bf(acc[mi][ni][r]);
        *(us4*)&vT[(size_t)col2 * 8192 + row] = pk;
      }
    }
  }
}

// ---------------- bf16 GEMM (2-barrier, BK=64), o-proj: f32 out + bias -------
template <int NT>
__global__ __launch_bounds__(256) void gemm_bt(
    const unsigned short* __restrict__ A,   // [M][K] bf16 bits
    const unsigned short* __restrict__ Bw,  // [N][K] bf16 bits
    float* __restrict__ Cf,                 // f32 out
    const float* __restrict__ bias,
    int K, int N) {
  __shared__ __align__(16) unsigned short As[128 * 64];
  __shared__ __align__(16) unsigned short Bs[128 * 64];

  const int bid = blockIdx.x;
  const int xcd = bid & 7;
  const int loc = bid >> 3;
  const int m0 = (xcd * 8 + loc / NT) * 128;
  const int n0 = (loc % NT) * 128;

  const int t = threadIdx.x;
  const int lane = t & 63;
  const int w = t >> 6;
  const int lr = lane & 15;
  const int lg = lane >> 4;
  const int wm = w >> 1;
  const int wn = w & 1;

  f32x4 acc[4][4];
#pragma unroll
  for (int i = 0; i < 4; ++i)
#pragma unroll
    for (int j = 0; j < 4; ++j) acc[i][j] = (f32x4){0.f, 0.f, 0.f, 0.f};

  const int srow = t >> 3;
  const int gs = (t & 7) ^ ((t >> 3) & 7);
  const unsigned short* ga = A + (size_t)(m0 + srow) * K + gs * 8;
  const unsigned short* gb = Bw + (size_t)(n0 + srow) * K + gs * 8;

  const int rsw = lr & 7;

  for (int k0 = 0; k0 < K; k0 += 64) {
#pragma unroll
    for (int k = 0; k < 4; ++k) {
      async16(ga + (size_t)(k * 32) * K + k0, &As[(k * 256 + t) * 8]);
      async16(gb + (size_t)(k * 32) * K + k0, &Bs[(k * 256 + t) * 8]);
    }
    __syncthreads();

#pragma unroll
    for (int kk = 0; kk < 2; ++kk) {
      const int slot = ((kk * 4 + lg) ^ rsw) * 8;
      bf16x8 af[4], bfr[4];
#pragma unroll
      for (int mi = 0; mi < 4; ++mi)
        af[mi] = *(const bf16x8*)&As[(wm * 64 + mi * 16 + lr) * 64 + slot];
#pragma unroll
      for (int ni = 0; ni < 4; ++ni)
        bfr[ni] = *(const bf16x8*)&Bs[(wn * 64 + ni * 16 + lr) * 64 + slot];
#pragma unroll
      for (int mi = 0; mi < 4; ++mi)
#pragma unroll
        for (int ni = 0; ni < 4; ++ni)
          acc[mi][ni] = __builtin_amdgcn_mfma_f32_16x16x32_bf16(
              af[mi], bfr[ni], acc[mi][ni], 0, 0, 0);
    }
    __syncthreads();
  }

#pragma unroll
  for (int mi = 0; mi < 4; ++mi) {
    const int row = m0 + wm * 64 + mi * 16 + lg * 4;
#pragma unroll
    for (int ni = 0; ni < 4; ++ni) {
      const int col = n0 + wn * 64 + ni * 16 + lr;
#pragma unroll
      for (int r = 0; r < 4; ++r)
        Cf[(size_t)(row + r) * N + col] = acc[mi][ni][r] + bias[col];
    }
  }
}

// ---------------- causal flash attention (4 waves x 32 q-rows, 32x32 MFMA) ----
// qk: [8192][2048] bf16 (cols 0..1023 Q pre-scaled, 1024..2047 K)
// vT: [1024][8192] bf16 (row = h*64+d, col = b*T + t)  -> V^T staged via
//     async16 like K (no in-kernel transpose / VSCATTER).
// ob: [8192][1024] bf16 attention output (col = h*64+d)
//
// 1024 blocks = 64 (b,h) pairs x 16 q-groups of 128 rows; 4 waves x 32 q-rows.
// KVBLK=64, 32KB LDS -> 4 blocks/CU, whole grid co-resident; snake qg mapping
// keeps per-CU work sums constant.
__global__ __launch_bounds__(256, 4) void attn_kernel(
    const unsigned short* __restrict__ qk, const unsigned short* __restrict__ vT,
    unsigned short* __restrict__ ob) {
  const int bid = blockIdx.x;
  const int pair = bid & 63;
  const int g = bid >> 6;               // 0..15, dispatch round-major
  const int rnd = g >> 2, idx = g & 3;
  const int qg = (rnd == 0) ? (15 - idx)
               : (rnd == 1) ? (8 + idx)
               : (rnd == 2) ? (7 - idx) : idx;   // CU sums constant
  const int b = pair >> 4;
  const int h = pair & 15;
  const int t = threadIdx.x;
  const int w = t >> 6;                 // 0..3
  const int lane = t & 63;
  const int l31 = lane & 31;
  const int hi = lane >> 5;

  const int q0w = qg * 128 + w * 32;       // wave's q strip
  const int myBound = 2 * qg + (w >> 1);   // last kv-tile this wave computes
  const int NT = 2 * qg + 2;               // 64-row kv tiles staged by block

  __shared__ __align__(16) unsigned short Ks[2][64 * 64];  // K rows, slot-swz
  __shared__ __align__(16) unsigned short Vs[2][64 * 64];  // V^T rows, slot-swz

  const size_t rowbase = (size_t)(b * T_) * NQK;

  // ---- Q B-fragments: col=q=l31, k=d = m*16 + hi*8 + i ----
  bf16x8 Qf[4];
  {
    const unsigned short* qp =
        qk + rowbase + (size_t)(q0w + l31) * NQK + h * 64 + hi * 8;
#pragma unroll
    for (int m = 0; m < 4; ++m) Qf[m] = *(const bf16x8*)(qp + m * 16);
  }

  // ---- staging geometry (256 threads, 2 async16 each for K and for V^T) ----
  // row r, LDS slot s holds global chunk s ^ (r&7)  (both-sides XOR swizzle).
  const int kr = t >> 3;                // 0..31 (+32 via second call)
  const int gsw = ((t & 7) ^ (kr & 7)) * 8;
  const unsigned short* kbase =
      qk + rowbase + 1024 + h * 64 + gsw + (size_t)kr * NQK;
  const unsigned short* vbase =
      vT + (size_t)(h * 64 + kr) * 8192 + (size_t)(b * T_) + gsw;

  float m_i = -INFINITY, l_i = 0.f;
  f32x16 o[2];
#pragma unroll
  for (int r = 0; r < 16; ++r) { o[0][r] = 0.f; o[1][r] = 0.f; }

  // ---- prologue: stage tile 0 into buffer 0 ----
  {
    async16(kbase, &Ks[0][t * 8]);
    async16(kbase + (size_t)32 * NQK, &Ks[0][2048 + t * 8]);
    async16(vbase, &Vs[0][t * 8]);
    async16(vbase + (size_t)32 * 8192, &Vs[0][2048 + t * 8]);
  }

  int cur = 0;
  for (int kt = 0; kt < NT; ++kt) {
    __syncthreads();  // buf[cur] ready (vmcnt(0) drains all async16)

    if (kt + 1 < NT) {
      const size_t ko = (size_t)(kt + 1) * 64 * NQK;
      const size_t vo = (size_t)(kt + 1) * 64;
      async16(kbase + ko, &Ks[cur ^ 1][t * 8]);
      async16(kbase + ko + (size_t)32 * NQK, &Ks[cur ^ 1][2048 + t * 8]);
      async16(vbase + vo, &Vs[cur ^ 1][t * 8]);
      async16(vbase + vo + (size_t)32 * 8192, &Vs[cur ^ 1][2048 + t * 8]);
    }

    if (kt <= myBound) {
      const unsigned short* Kb = Ks[cur];
      const unsigned short* Vb = Vs[cur];
      const int r7 = l31 & 7;

      // ---- S^T[kv][q] : 2 kv-subtiles of 32 ----
      f32x16 a0, a1;
#pragma unroll
      for (int r = 0; r < 16; ++r) { a0[r] = 0.f; a1[r] = 0.f; }
      {
        const int rb0 = l31 * 64;
        const int rb1 = (32 + l31) * 64;
        __builtin_amdgcn_s_setprio(1);
#pragma unroll
        for (int m = 0; m < 4; ++m) {
          const int c = (((m << 1) | hi) ^ r7) * 8;
          bf16x8 kf0 = *(const bf16x8*)&Kb[rb0 + c];
          bf16x8 kf1 = *(const bf16x8*)&Kb[rb1 + c];
          a0 = __builtin_amdgcn_mfma_f32_32x32x16_bf16(kf0, Qf[m], a0, 0, 0, 0);
          a1 = __builtin_amdgcn_mfma_f32_32x32x16_bf16(kf1, Qf[m], a1, 0, 0, 0);
        }
        __builtin_amdgcn_s_setprio(0);
      }

      // ---- causal mask: only the diagonal-crossing tile ----
      if (kt == myBound) {
        const int qglob = q0w + l31;
#pragma unroll
        for (int r = 0; r < 16; ++r) {
          const int kvb = kt * 64 + (r & 3) + ((r >> 2) << 3) + (hi << 2);
          if (kvb > qglob) a0[r] = -INFINITY;
          if (kvb + 32 > qglob) a1[r] = -INFINITY;
        }
      }

      // ---- online softmax: tree max, defer-max (THR=8 in log2 space) ----
      float m8[8];
#pragma unroll
      for (int j2 = 0; j2 < 8; ++j2)
        m8[j2] = fmaxf(fmaxf(a0[j2], a0[j2 + 8]), fmaxf(a1[j2], a1[j2 + 8]));
      float pp = fmaxf(fmaxf(fmaxf(m8[0], m8[4]), fmaxf(m8[1], m8[5])),
                       fmaxf(fmaxf(m8[2], m8[6]), fmaxf(m8[3], m8[7])));
      float pmax;
      XHALF(pmax, pp, fmaxf);
      if (__any(pmax > m_i + 8.f)) {
        const float mnew = fmaxf(m_i, pmax);
        const float al = fast_exp2(m_i - mnew);
        m_i = mnew;
        l_i *= al;
#pragma unroll
        for (int r = 0; r < 16; ++r) { o[0][r] *= al; o[1][r] *= al; }
      }

#pragma unroll
      for (int r = 0; r < 16; ++r) {
        a0[r] = fast_exp2(a0[r] - m_i);
        a1[r] = fast_exp2(a1[r] - m_i);
      }
      float s8[8];
#pragma unroll
      for (int j2 = 0; j2 < 8; ++j2)
        s8[j2] = (a0[j2] + a0[j2 + 8]) + (a1[j2] + a1[j2 + 8]);
      float rp = ((s8[0] + s8[1]) + (s8[2] + s8[3])) +
                 ((s8[4] + s8[5]) + (s8[6] + s8[7]));
      float rs;
      XHALF(rs, rp, fadd_);
      l_i += rs;

      // ---- P^T B-fragments: cvt_pk pairs + permlane32_swap half-exchange ----
      bf16x8 Pf[4];
#pragma unroll
      for (int m = 0; m < 4; ++m) {
        const int rb2 = (m & 1) * 8;
        uint32_t u0, u1, u2, u3;
        const f32x16& s = (m >> 1) ? a1 : a0;
        asm("v_cvt_pk_bf16_f32 %0, %1, %2" : "=v"(u0) : "v"(s[rb2 + 0]), "v"(s[rb2 + 1]));
        asm("v_cvt_pk_bf16_f32 %0, %1, %2" : "=v"(u1) : "v"(s[rb2 + 2]), "v"(s[rb2 + 3]));
        asm("v_cvt_pk_bf16_f32 %0, %1, %2" : "=v"(u2) : "v"(s[rb2 + 4]), "v"(s[rb2 + 5]));
        asm("v_cvt_pk_bf16_f32 %0, %1, %2" : "=v"(u3) : "v"(s[rb2 + 6]), "v"(s[rb2 + 7]));
        asm("v_permlane32_swap_b32 %0, %1" : "+v"(u0), "+v"(u2));
        asm("v_permlane32_swap_b32 %0, %1" : "+v"(u1), "+v"(u3));
        u32x4 pw = {u0, u1, u2, u3};
        Pf[m] = __builtin_bit_cast(bf16x8, pw);
      }

      // ---- O^T += V^T P^T  (V^T rows straight from LDS, same swz as K) ----
      __builtin_amdgcn_s_setprio(1);
#pragma unroll
      for (int dt = 0; dt < 2; ++dt) {
        const int base = (dt * 32 + l31) * 64;
#pragma unroll
        for (int m = 0; m < 4; ++m) {
          const int c = (((m << 1) | hi) ^ r7) * 8;
          bf16x8 vf = *(const bf16x8*)&Vb[base + c];
          o[dt] = __builtin_amdgcn_mfma_f32_32x32x16_bf16(vf, Pf[m], o[dt], 0, 0, 0);
        }
      }
      __builtin_amdgcn_s_setprio(0);
    }

    cur ^= 1;
  }

  // ---- epilogue: normalize, pack to bf16, swap to contiguous d-runs, store --
  const float rl = 1.0f / l_i;
#pragma unroll
  for (int dt = 0; dt < 2; ++dt) {
    float s[16];
#pragma unroll
    for (int r = 0; r < 16; ++r) s[r] = o[dt][r] * rl;
    uint32_t u[8];
#pragma unroll
    for (int p = 0; p < 8; ++p)
      asm("v_cvt_pk_bf16_f32 %0, %1, %2" : "=v"(u[p]) : "v"(s[2 * p]), "v"(s[2 * p + 1]));
    asm("v_permlane32_swap_b32 %0, %1" : "+v"(u[0]), "+v"(u[2]));
    asm("v_permlane32_swap_b32 %0, %1" : "+v"(u[1]), "+v"(u[3]));
    asm("v_permlane32_swap_b32 %0, %1" : "+v"(u[4]), "+v"(u[6]));
    asm("v_permlane32_swap_b32 %0, %1" : "+v"(u[5]), "+v"(u[7]));
    unsigned short* op =
        ob + (size_t)(b * T_ + q0w + l31) * 1024 + h * 64 + dt * 32 + hi * 8;
    u32x4 c0 = {u[0], u[1], u[2], u[3]};   // d = dt*32 + hi*8 + [0..8)
    u32x4 c1 = {u[4], u[5], u[6], u[7]};   // d = dt*32 + 16 + hi*8 + [0..8)
    *(u32x4*)op = c0;
    *(u32x4*)(op + 16) = c1;
  }
}

// ---------------- host launch ----------------
extern "C" void kernel_launch(void* const* d_in, const int* in_sizes, int n_in,
                              void* d_out, int out_size, void* d_ws,
                              size_t ws_size, hipStream_t stream) {
  const float* x = (const float*)d_in[0];
  const float* Wq = (const float*)d_in[1];
  const float* Wk = (const float*)d_in[2];
  const float* Wv = (const float*)d_in[3];
  const float* Wo = (const float*)d_in[4];
  const float* bo = (const float*)d_in[5];
  float* out = (float*)d_out;

  char* ws = (char*)d_ws;
  unsigned short* xb   = (unsigned short*)(ws + 0);          // 16 MB
  unsigned short* wqkv = (unsigned short*)(ws + 16777216);   // 6 MB
  unsigned short* wo   = (unsigned short*)(ws + 23068672);   // 2 MB
  unsigned short* qk   = (unsigned short*)(ws + 25165824);   // 32 MB
  unsigned short* vT   = (unsigned short*)(ws + 58720256);   // 16 MB
  unsigned short* ob   = (unsigned short*)(ws + 75497472);   // 16 MB
  if (ws_size < 92274688u) return;

  cvt_all<<<12288, 256, 0, stream>>>(x, Wq, Wk, Wv, Wo, xb, wqkv, wo);

  // fused QKV projection: QK -> qk[8192][2048]; V -> vT[1024][8192] transposed
  gemm_qkv<<<768, 512, 0, stream>>>(xb, wqkv, qk, vT);

  // causal flash attention (V^T async-staged; snake mapping, 4 blocks/CU)
  attn_kernel<<<dim3(1024), 256, 0, stream>>>(qk, vT, ob);

  // output projection + bias
  gemm_bt<8><<<512, 256, 0, stream>>>(ob, wo, out, bo, 1024, 1024);
}

// Round 14
// 153.043 us; speedup vs baseline: 1.1273x; 1.0078x over previous
//
#include <hip/hip_runtime.h>
#include <hip/hip_bf16.h>
#include <stdint.h>

// Problem constants
#define B_   4
#define T_   2048
#define H_   16
#define MTOT (B_ * T_)          // 8192 rows
#define NQK  2048               // QK buffer cols (Q 0..1023, K 1024..2047)
#define QSC  0.18033688f        // 0.125 * log2(e): fold softmax scale + exp2 conversion into Q

typedef __attribute__((ext_vector_type(8))) __bf16 bf16x8;
typedef __attribute__((ext_vector_type(4))) float f32x4;
typedef __attribute__((ext_vector_type(16))) float f32x16;
typedef __attribute__((ext_vector_type(4))) float f4v;
typedef __attribute__((ext_vector_type(4))) unsigned short us4;
typedef __attribute__((ext_vector_type(8))) unsigned short us8;
typedef __attribute__((ext_vector_type(4))) unsigned int u32x4;

static __device__ __forceinline__ unsigned short f2bf(float f) {
  __hip_bfloat16 h = __float2bfloat16(f);
  return __builtin_bit_cast(unsigned short, h);
}

static __device__ __forceinline__ float fast_exp2(float x) {
#if __has_builtin(__builtin_amdgcn_exp2f)
  return __builtin_amdgcn_exp2f(x);
#else
  float r; asm("v_exp_f32 %0, %1" : "=v"(r) : "v"(x)); return r;
#endif
}

static __device__ __forceinline__ void async16(const void* g, void* l) {
  __builtin_amdgcn_global_load_lds(
      (const __attribute__((address_space(1))) void*)g,
      (__attribute__((address_space(3))) void*)l, 16, 0, 0);
}

// cross-half (lane ^ 32) reduce via permlane32_swap (VALU) instead of
// ds_bpermute (__shfl_xor).
#define XHALF(res, x, OP)                                  \
  {                                                        \
    float t1_ = (x), t2_ = (x);                            \
    asm("" : "+v"(t2_));                                   \
    asm("v_permlane32_swap_b32 %0, %1" : "+v"(t1_), "+v"(t2_)); \
    res = OP(t1_, t2_);                                    \
  }
static __device__ __forceinline__ float fadd_(float a, float b) { return a + b; }

// ---------------- fused fp32 -> bf16 convert (x4 vectorized, 1 launch) --------
__global__ __launch_bounds__(256) void cvt_all(
    const float* __restrict__ x, const float* __restrict__ Wq,
    const float* __restrict__ Wk, const float* __restrict__ Wv,
    const float* __restrict__ Wo, unsigned short* __restrict__ xb,
    unsigned short* __restrict__ wqkv, unsigned short* __restrict__ wo) {
  int i = blockIdx.x * blockDim.x + threadIdx.x;
  const float* s; unsigned short* d; int j;
  if (i < 2097152)      { s = x;  d = xb;             j = i; }
  else if (i < 2359296) { s = Wq; d = wqkv;           j = i - 2097152; }
  else if (i < 2621440) { s = Wk; d = wqkv + 1048576; j = i - 2359296; }
  else if (i < 2883584) { s = Wv; d = wqkv + 2097152; j = i - 2621440; }
  else                  { s = Wo; d = wo;             j = i - 2883584; }
  f4v v = reinterpret_cast<const f4v*>(s)[j];
  us4 o;
  o.x = f2bf(v.x); o.y = f2bf(v.y); o.z = f2bf(v.z); o.w = f2bf(v.w);
  reinterpret_cast<us4*>(d)[j] = o;
}

// ---------------- QKV GEMM: BM=128 x BN=256, BK=64, 512 threads --------------
// 2-barrier structure + both-sides K-slot XOR swizzle (proven). Epilogue:
//  - n0 < 2048  (QK blocks): bf16 -> qk[8192][2048], Q cols scaled by QSC.
//  - n0 >= 2048 (V blocks):  transposed via LDS (48KB free after K-loop):
//    stage C^T half-tile [128 n][128 m] in LDS (row stride 136 -> 16B-aligned
//    b128 reads), then fully-coalesced 256B-segment us8 stores to vT[1024][8192].
__global__ __launch_bounds__(512) void gemm_qkv(
    const unsigned short* __restrict__ A,    // [8192][1024] bf16
    const unsigned short* __restrict__ Bw,   // [3072][1024] bf16
    unsigned short* __restrict__ Cqk,        // [8192][2048]
    unsigned short* __restrict__ vT) {       // [1024][8192]
  const int K = 1024;
  __shared__ __align__(16) unsigned short Sh[128 * 64 + 256 * 64];  // 48KB
  unsigned short* const As = Sh;              // [128][64]
  unsigned short* const Bs = Sh + 128 * 64;   // [256][64]

  const int bid = blockIdx.x;
  const int xcd = bid & 7;
  const int loc = bid >> 3;              // 0..95
  const int m0 = (xcd * 8 + loc / 12) * 128;
  const int n0 = (loc % 12) * 256;

  const int t = threadIdx.x;
  const int lane = t & 63;
  const int w = t >> 6;
  const int lr = lane & 15;
  const int lg = lane >> 4;
  const int wm = w >> 2;                 // 0..1
  const int wn = w & 3;                  // 0..3

  f32x4 acc[4][4];
#pragma unroll
  for (int i = 0; i < 4; ++i)
#pragma unroll
    for (int j = 0; j < 4; ++j) acc[i][j] = (f32x4){0.f, 0.f, 0.f, 0.f};

  const int srow = t >> 3;                      // 0..63
  const int gs = (t & 7) ^ (srow & 7);          // inverse-swizzled source slot
  const unsigned short* ga = A + (size_t)(m0 + srow) * K + gs * 8;
  const unsigned short* gb = Bw + (size_t)(n0 + srow) * K + gs * 8;
  const int rsw = lr & 7;

  for (int k0 = 0; k0 < K; k0 += 64) {
#pragma unroll
    for (int k = 0; k < 2; ++k)
      async16(ga + (size_t)(k * 64) * K + k0, &As[(k * 512 + t) * 8]);
#pragma unroll
    for (int k = 0; k < 4; ++k)
      async16(gb + (size_t)(k * 64) * K + k0, &Bs[(k * 512 + t) * 8]);
    __syncthreads();

#pragma unroll
    for (int kk = 0; kk < 2; ++kk) {
      const int slot = ((kk * 4 + lg) ^ rsw) * 8;
      bf16x8 af[4], bfr[4];
#pragma unroll
      for (int mi = 0; mi < 4; ++mi)
        af[mi] = *(const bf16x8*)&As[(wm * 64 + mi * 16 + lr) * 64 + slot];
#pragma unroll
      for (int ni = 0; ni < 4; ++ni)
        bfr[ni] = *(const bf16x8*)&Bs[(wn * 64 + ni * 16 + lr) * 64 + slot];
#pragma unroll
      for (int mi = 0; mi < 4; ++mi)
#pragma unroll
        for (int ni = 0; ni < 4; ++ni)
          acc[mi][ni] = __builtin_amdgcn_mfma_f32_16x16x32_bf16(
              af[mi], bfr[ni], acc[mi][ni], 0, 0, 0);
    }
    __syncthreads();
  }

  // epilogue: D layout col=lane&15, row=(lane>>4)*4+r
  if (n0 < 2048) {
#pragma unroll
    for (int mi = 0; mi < 4; ++mi) {
      const int row = m0 + wm * 64 + mi * 16 + lg * 4;
#pragma unroll
      for (int ni = 0; ni < 4; ++ni) {
        const int col = n0 + wn * 64 + ni * 16 + lr;
        const float sc = (col < 1024) ? QSC : 1.0f;
#pragma unroll
        for (int r = 0; r < 4; ++r)
          Cqk[(size_t)(row + r) * NQK + col] = f2bf(acc[mi][ni][r] * sc);
      }
    }
  } else {
    // V block: LDS-staged transpose, two 128-n halves. Sh free after K-loop.
#pragma unroll
    for (int hh = 0; hh < 2; ++hh) {
      if ((wn >> 1) == hh) {
        const int nl0 = (wn & 1) * 64;
        const int m = wm * 64 + lg * 4;
#pragma unroll
        for (int mi = 0; mi < 4; ++mi) {
#pragma unroll
          for (int ni = 0; ni < 4; ++ni) {
            const int nl = nl0 + ni * 16 + lr;
            us4 pk;
#pragma unroll
            for (int r = 0; r < 4; ++r) pk[r] = f2bf(acc[mi][ni][r]);
            *(us4*)&Sh[nl * 136 + m + mi * 16] = pk;
          }
        }
      }
      __syncthreads();
      // coalesced store: 4 passes, 16 threads per 256B vT row segment
#pragma unroll
      for (int p = 0; p < 4; ++p) {
        const int flat = p * 512 + t;
        const int row = flat >> 4;          // 0..127 (n within half)
        const int mo = (flat & 15) * 8;     // m offset, shorts
        us8 v = *(const us8*)&Sh[row * 136 + mo];
        *(us8*)&vT[(size_t)(n0 - 2048 + hh * 128 + row) * 8192 + m0 + mo] = v;
      }
      __syncthreads();
    }
  }
}

// ---------------- bf16 GEMM (2-barrier, BK=64), o-proj: f32 out + bias -------
template <int NT>
__global__ __launch_bounds__(256) void gemm_bt(
    const unsigned short* __restrict__ A,   // [M][K] bf16 bits
    const unsigned short* __restrict__ Bw,  // [N][K] bf16 bits
    float* __restrict__ Cf,                 // f32 out
    const float* __restrict__ bias,
    int K, int N) {
  __shared__ __align__(16) unsigned short As[128 * 64];
  __shared__ __align__(16) unsigned short Bs[128 * 64];

  const int bid = blockIdx.x;
  const int xcd = bid & 7;
  const int loc = bid >> 3;
  const int m0 = (xcd * 8 + loc / NT) * 128;
  const int n0 = (loc % NT) * 128;

  const int t = threadIdx.x;
  const int lane = t & 63;
  const int w = t >> 6;
  const int lr = lane & 15;
  const int lg = lane >> 4;
  const int wm = w >> 1;
  const int wn = w & 1;

  f32x4 acc[4][4];
#pragma unroll
  for (int i = 0; i < 4; ++i)
#pragma unroll
    for (int j = 0; j < 4; ++j) acc[i][j] = (f32x4){0.f, 0.f, 0.f, 0.f};

  const int srow = t >> 3;
  const int gs = (t & 7) ^ ((t >> 3) & 7);
  const unsigned short* ga = A + (size_t)(m0 + srow) * K + gs * 8;
  const unsigned short* gb = Bw + (size_t)(n0 + srow) * K + gs * 8;

  const int rsw = lr & 7;

  for (int k0 = 0; k0 < K; k0 += 64) {
#pragma unroll
    for (int k = 0; k < 4; ++k) {
      async16(ga + (size_t)(k * 32) * K + k0, &As[(k * 256 + t) * 8]);
      async16(gb + (size_t)(k * 32) * K + k0, &Bs[(k * 256 + t) * 8]);
    }
    __syncthreads();

#pragma unroll
    for (int kk = 0; kk < 2; ++kk) {
      const int slot = ((kk * 4 + lg) ^ rsw) * 8;
      bf16x8 af[4], bfr[4];
#pragma unroll
      for (int mi = 0; mi < 4; ++mi)
        af[mi] = *(const bf16x8*)&As[(wm * 64 + mi * 16 + lr) * 64 + slot];
#pragma unroll
      for (int ni = 0; ni < 4; ++ni)
        bfr[ni] = *(const bf16x8*)&Bs[(wn * 64 + ni * 16 + lr) * 64 + slot];
#pragma unroll
      for (int mi = 0; mi < 4; ++mi)
#pragma unroll
        for (int ni = 0; ni < 4; ++ni)
          acc[mi][ni] = __builtin_amdgcn_mfma_f32_16x16x32_bf16(
              af[mi], bfr[ni], acc[mi][ni], 0, 0, 0);
    }
    __syncthreads();
  }

#pragma unroll
  for (int mi = 0; mi < 4; ++mi) {
    const int row = m0 + wm * 64 + mi * 16 + lg * 4;
#pragma unroll
    for (int ni = 0; ni < 4; ++ni) {
      const int col = n0 + wn * 64 + ni * 16 + lr;
#pragma unroll
      for (int r = 0; r < 4; ++r)
        Cf[(size_t)(row + r) * N + col] = acc[mi][ni][r] + bias[col];
    }
  }
}

// ---------------- causal flash attention (4 waves x 32 q-rows, 32x32 MFMA) ----
// qk: [8192][2048] bf16 (cols 0..1023 Q pre-scaled, 1024..2047 K)
// vT: [1024][8192] bf16 (row = h*64+d, col = b*T + t)  -> V^T staged via
//     async16 like K (no in-kernel transpose).
// ob: [8192][1024] bf16 attention output (col = h*64+d)
__global__ __launch_bounds__(256, 4) void attn_kernel(
    const unsigned short* __restrict__ qk, const unsigned short* __restrict__ vT,
    unsigned short* __restrict__ ob) {
  const int bid = blockIdx.x;
  const int pair = bid & 63;
  const int g = bid >> 6;               // 0..15, dispatch round-major
  const int rnd = g >> 2, idx = g & 3;
  const int qg = (rnd == 0) ? (15 - idx)
               : (rnd == 1) ? (8 + idx)
               : (rnd == 2) ? (7 - idx) : idx;   // CU sums constant
  const int b = pair >> 4;
  const int h = pair & 15;
  const int t = threadIdx.x;
  const int w = t >> 6;                 // 0..3
  const int lane = t & 63;
  const int l31 = lane & 31;
  const int hi = lane >> 5;

  const int q0w = qg * 128 + w * 32;       // wave's q strip
  const int myBound = 2 * qg + (w >> 1);   // last kv-tile this wave computes
  const int NT = 2 * qg + 2;               // 64-row kv tiles staged by block

  __shared__ __align__(16) unsigned short Ks[2][64 * 64];  // K rows, slot-swz
  __shared__ __align__(16) unsigned short Vs[2][64 * 64];  // V^T rows, slot-swz

  const size_t rowbase = (size_t)(b * T_) * NQK;

  // ---- Q B-fragments: col=q=l31, k=d = m*16 + hi*8 + i ----
  bf16x8 Qf[4];
  {
    const unsigned short* qp =
        qk + rowbase + (size_t)(q0w + l31) * NQK + h * 64 + hi * 8;
#pragma unroll
    for (int m = 0; m < 4; ++m) Qf[m] = *(const bf16x8*)(qp + m * 16);
  }

  // ---- staging geometry (256 threads, 2 async16 each for K and for V^T) ----
  const int kr = t >> 3;                // 0..31 (+32 via second call)
  const int gsw = ((t & 7) ^ (kr & 7)) * 8;
  const unsigned short* kbase =
      qk + rowbase + 1024 + h * 64 + gsw + (size_t)kr * NQK;
  const unsigned short* vbase =
      vT + (size_t)(h * 64 + kr) * 8192 + (size_t)(b * T_) + gsw;

  float m_i = -INFINITY, l_i = 0.f;
  f32x16 o[2];
#pragma unroll
  for (int r = 0; r < 16; ++r) { o[0][r] = 0.f; o[1][r] = 0.f; }

  // ---- prologue: stage tile 0 into buffer 0 ----
  {
    async16(kbase, &Ks[0][t * 8]);
    async16(kbase + (size_t)32 * NQK, &Ks[0][2048 + t * 8]);
    async16(vbase, &Vs[0][t * 8]);
    async16(vbase + (size_t)32 * 8192, &Vs[0][2048 + t * 8]);
  }

  int cur = 0;
  for (int kt = 0; kt < NT; ++kt) {
    __syncthreads();  // buf[cur] ready (vmcnt(0) drains all async16)

    if (kt + 1 < NT) {
      const size_t ko = (size_t)(kt + 1) * 64 * NQK;
      const size_t vo = (size_t)(kt + 1) * 64;
      async16(kbase + ko, &Ks[cur ^ 1][t * 8]);
      async16(kbase + ko + (size_t)32 * NQK, &Ks[cur ^ 1][2048 + t * 8]);
      async16(vbase + vo, &Vs[cur ^ 1][t * 8]);
      async16(vbase + vo + (size_t)32 * 8192, &Vs[cur ^ 1][2048 + t * 8]);
    }

    if (kt <= myBound) {
      const unsigned short* Kb = Ks[cur];
      const unsigned short* Vb = Vs[cur];
      const int r7 = l31 & 7;

      // ---- S^T[kv][q] : 2 kv-subtiles of 32 ----
      f32x16 a0, a1;
#pragma unroll
      for (int r = 0; r < 16; ++r) { a0[r] = 0.f; a1[r] = 0.f; }
      {
        const int rb0 = l31 * 64;
        const int rb1 = (32 + l31) * 64;
        __builtin_amdgcn_s_setprio(1);
#pragma unroll
        for (int m = 0; m < 4; ++m) {
          const int c = (((m << 1) | hi) ^ r7) * 8;
          bf16x8 kf0 = *(const bf16x8*)&Kb[rb0 + c];
          bf16x8 kf1 = *(const bf16x8*)&Kb[rb1 + c];
          a0 = __builtin_amdgcn_mfma_f32_32x32x16_bf16(kf0, Qf[m], a0, 0, 0, 0);
          a1 = __builtin_amdgcn_mfma_f32_32x32x16_bf16(kf1, Qf[m], a1, 0, 0, 0);
        }
        __builtin_amdgcn_s_setprio(0);
      }

      // ---- causal mask: only the diagonal-crossing tile ----
      if (kt == myBound) {
        const int qglob = q0w + l31;
#pragma unroll
        for (int r = 0; r < 16; ++r) {
          const int kvb = kt * 64 + (r & 3) + ((r >> 2) << 3) + (hi << 2);
          if (kvb > qglob) a0[r] = -INFINITY;
          if (kvb + 32 > qglob) a1[r] = -INFINITY;
        }
      }

      // ---- online softmax: tree max, defer-max (THR=8 in log2 space) ----
      float m8[8];
#pragma unroll
      for (int j2 = 0; j2 < 8; ++j2)
        m8[j2] = fmaxf(fmaxf(a0[j2], a0[j2 + 8]), fmaxf(a1[j2], a1[j2 + 8]));
      float pp = fmaxf(fmaxf(fmaxf(m8[0], m8[4]), fmaxf(m8[1], m8[5])),
                       fmaxf(fmaxf(m8[2], m8[6]), fmaxf(m8[3], m8[7])));
      float pmax;
      XHALF(pmax, pp, fmaxf);
      if (__any(pmax > m_i + 8.f)) {
        const float mnew = fmaxf(m_i, pmax);
        const float al = fast_exp2(m_i - mnew);
        m_i = mnew;
        l_i *= al;
#pragma unroll
        for (int r = 0; r < 16; ++r) { o[0][r] *= al; o[1][r] *= al; }
      }

#pragma unroll
      for (int r = 0; r < 16; ++r) {
        a0[r] = fast_exp2(a0[r] - m_i);
        a1[r] = fast_exp2(a1[r] - m_i);
      }
      float s8[8];
#pragma unroll
      for (int j2 = 0; j2 < 8; ++j2)
        s8[j2] = (a0[j2] + a0[j2 + 8]) + (a1[j2] + a1[j2 + 8]);
      float rp = ((s8[0] + s8[1]) + (s8[2] + s8[3])) +
                 ((s8[4] + s8[5]) + (s8[6] + s8[7]));
      float rs;
      XHALF(rs, rp, fadd_);
      l_i += rs;

      // ---- P^T B-fragments: cvt_pk pairs + permlane32_swap half-exchange ----
      bf16x8 Pf[4];
#pragma unroll
      for (int m = 0; m < 4; ++m) {
        const int rb2 = (m & 1) * 8;
        uint32_t u0, u1, u2, u3;
        const f32x16& s = (m >> 1) ? a1 : a0;
        asm("v_cvt_pk_bf16_f32 %0, %1, %2" : "=v"(u0) : "v"(s[rb2 + 0]), "v"(s[rb2 + 1]));
        asm("v_cvt_pk_bf16_f32 %0, %1, %2" : "=v"(u1) : "v"(s[rb2 + 2]), "v"(s[rb2 + 3]));
        asm("v_cvt_pk_bf16_f32 %0, %1, %2" : "=v"(u2) : "v"(s[rb2 + 4]), "v"(s[rb2 + 5]));
        asm("v_cvt_pk_bf16_f32 %0, %1, %2" : "=v"(u3) : "v"(s[rb2 + 6]), "v"(s[rb2 + 7]));
        asm("v_permlane32_swap_b32 %0, %1" : "+v"(u0), "+v"(u2));
        asm("v_permlane32_swap_b32 %0, %1" : "+v"(u1), "+v"(u3));
        u32x4 pw = {u0, u1, u2, u3};
        Pf[m] = __builtin_bit_cast(bf16x8, pw);
      }

      // ---- O^T += V^T P^T  (V^T rows straight from LDS, same swz as K) ----
      __builtin_amdgcn_s_setprio(1);
#pragma unroll
      for (int dt = 0; dt < 2; ++dt) {
        const int base = (dt * 32 + l31) * 64;
#pragma unroll
        for (int m = 0; m < 4; ++m) {
          const int c = (((m << 1) | hi) ^ r7) * 8;
          bf16x8 vf = *(const bf16x8*)&Vb[base + c];
          o[dt] = __builtin_amdgcn_mfma_f32_32x32x16_bf16(vf, Pf[m], o[dt], 0, 0, 0);
        }
      }
      __builtin_amdgcn_s_setprio(0);
    }

    cur ^= 1;
  }

  // ---- epilogue: normalize, pack to bf16, swap to contiguous d-runs, store --
  const float rl = 1.0f / l_i;
#pragma unroll
  for (int dt = 0; dt < 2; ++dt) {
    float s[16];
#pragma unroll
    for (int r = 0; r < 16; ++r) s[r] = o[dt][r] * rl;
    uint32_t u[8];
#pragma unroll
    for (int p = 0; p < 8; ++p)
      asm("v_cvt_pk_bf16_f32 %0, %1, %2" : "=v"(u[p]) : "v"(s[2 * p]), "v"(s[2 * p + 1]));
    asm("v_permlane32_swap_b32 %0, %1" : "+v"(u[0]), "+v"(u[2]));
    asm("v_permlane32_swap_b32 %0, %1" : "+v"(u[1]), "+v"(u[3]));
    asm("v_permlane32_swap_b32 %0, %1" : "+v"(u[4]), "+v"(u[6]));
    asm("v_permlane32_swap_b32 %0, %1" : "+v"(u[5]), "+v"(u[7]));
    unsigned short* op =
        ob + (size_t)(b * T_ + q0w + l31) * 1024 + h * 64 + dt * 32 + hi * 8;
    u32x4 c0 = {u[0], u[1], u[2], u[3]};   // d = dt*32 + hi*8 + [0..8)
    u32x4 c1 = {u[4], u[5], u[6], u[7]};   // d = dt*32 + 16 + hi*8 + [0..8)
    *(u32x4*)op = c0;
    *(u32x4*)(op + 16) = c1;
  }
}

// ---------------- host launch ----------------
extern "C" void kernel_launch(void* const* d_in, const int* in_sizes, int n_in,
                              void* d_out, int out_size, void* d_ws,
                              size_t ws_size, hipStream_t stream) {
  const float* x = (const float*)d_in[0];
  const float* Wq = (const float*)d_in[1];
  const float* Wk = (const float*)d_in[2];
  const float* Wv = (const float*)d_in[3];
  const float* Wo = (const float*)d_in[4];
  const float* bo = (const float*)d_in[5];
  float* out = (float*)d_out;

  char* ws = (char*)d_ws;
  unsigned short* xb   = (unsigned short*)(ws + 0);          // 16 MB
  unsigned short* wqkv = (unsigned short*)(ws + 16777216);   // 6 MB
  unsigned short* wo   = (unsigned short*)(ws + 23068672);   // 2 MB
  unsigned short* qk   = (unsigned short*)(ws + 25165824);   // 32 MB
  unsigned short* vT   = (unsigned short*)(ws + 58720256);   // 16 MB
  unsigned short* ob   = (unsigned short*)(ws + 75497472);   // 16 MB
  if (ws_size < 92274688u) return;

  cvt_all<<<12288, 256, 0, stream>>>(x, Wq, Wk, Wv, Wo, xb, wqkv, wo);

  // fused QKV projection: QK -> qk[8192][2048]; V -> vT[1024][8192] transposed
  gemm_qkv<<<768, 512, 0, stream>>>(xb, wqkv, qk, vT);

  // causal flash attention (V^T async-staged; snake mapping, 4 blocks/CU)
  attn_kernel<<<dim3(1024), 256, 0, stream>>>(qk, vT, ob);

  // output projection + bias
  gemm_bt<8><<<512, 256, 0, stream>>>(ob, wo, out, bo, 1024, 1024);
}